// Round 8
// baseline (2197.935 us; speedup 1.0000x reference)
//
#include <hip/hip_runtime.h>
#include <cstdint>

typedef _Float16 f16;
typedef _Float16 f16x2 __attribute__((ext_vector_type(2)));

#define T_STEPS 512
#define B_SZ 512
#define LOG2PI 1.8378770664093453f

// Raw barrier: drain LDS only (NOT vmcnt) so in-flight global prefetch loads
// and stores survive across the barrier.
__device__ __forceinline__ void barrier_lds() {
  asm volatile("s_waitcnt lgkmcnt(0)" ::: "memory");
  __builtin_amdgcn_s_barrier();
  asm volatile("" ::: "memory");
}

__device__ __forceinline__ uint32_t packh2(float a, float b) {
  f16x2 v; v[0] = (f16)a; v[1] = (f16)b;
  return __builtin_bit_cast(uint32_t, v);
}

__device__ __forceinline__ float fdot2(uint32_t a, uint32_t b, float c) {
#if defined(__AMDGCN__) && __has_builtin(__builtin_amdgcn_fdot2)
  return __builtin_amdgcn_fdot2(__builtin_bit_cast(f16x2, a),
                                __builtin_bit_cast(f16x2, b), c, false);
#else
  f16x2 x = __builtin_bit_cast(f16x2, a), y = __builtin_bit_cast(f16x2, b);
  return c + (float)x[0] * (float)y[0] + (float)x[1] * (float)y[1];
#endif
}

#define DOT4(acc, w0, w1, w2, w3, v)                                     \
  do {                                                                   \
    acc = fdot2((w0), (v).x, acc); acc = fdot2((w1), (v).y, acc);        \
    acc = fdot2((w2), (v).z, acc); acc = fdot2((w3), (v).w, acc);        \
  } while (0)

__device__ __forceinline__ float sigmoidf_(float x) {
  return 1.0f / (1.0f + __expf(-x));
}
__device__ __forceinline__ float tanhf_(float x) {
  float ax = fabsf(x);
  float t = __expf(-2.0f * ax);
  float r = (1.0f - t) / (1.0f + t);
  return copysignf(r, x);
}
__device__ __forceinline__ float softplusf_(float x) {
  return fmaxf(x, 0.0f) + __logf(1.0f + __expf(-fabsf(x)));
}

// ---------------------------------------------------------------------------
// Kernel 1: embedding / state_t construction.  state_t: (T,B,32) f16.
// ---------------------------------------------------------------------------
__global__ __launch_bounds__(256) void k_embed(
    const float* __restrict__ xs, const float* __restrict__ shot_emb,
    const float* __restrict__ player_emb, f16* __restrict__ state_t,
    float* __restrict__ accums) {
  if (blockIdx.x == 0 && threadIdx.x < 16) accums[threadIdx.x] = 0.0f;
  size_t idx = (size_t)blockIdx.x * 256 + threadIdx.x;
  const float* xp = xs + idx * 23;
  f16* op = state_t + idx * 32;
  int sid = (int)xp[12];
  int pid = (int)xp[17];
#pragma unroll
  for (int i = 0; i < 12; ++i) op[i] = (f16)xp[i];
  const float* se = shot_emb + sid * 8;
#pragma unroll
  for (int i = 0; i < 8; ++i) op[12 + i] = (f16)se[i];
#pragma unroll
  for (int i = 0; i < 4; ++i) op[20 + i] = (f16)xp[13 + i];
  const float* pe = player_emb + pid * 8;
#pragma unroll
  for (int i = 0; i < 8; ++i) op[24 + i] = (f16)pe[i];
}

// ---------------------------------------------------------------------------
// Kernel 1b: g-network lookup table (R6-verified).  16 x 65536 f32 = 4 MB.
// ---------------------------------------------------------------------------
__global__ __launch_bounds__(256) void k_gtab(
    const float* __restrict__ gw1, const float* __restrict__ gb1,
    const float* __restrict__ gw2, const float* __restrict__ gb2,
    float* __restrict__ g_tab) {
  int gid = blockIdx.x * 256 + threadIdx.x;
  int l = gid >> 16, yi = gid & 0xffff;
  f16 hy = __builtin_bit_cast(f16, (unsigned short)yi);
  float y = (float)hy;
  const float* w1 = gw1 + l * 128;
  const float* b1 = gb1 + l * 128;
  const float* w2 = gw2 + l * 128;
  float a0 = 0.f, a1 = 0.f;
#pragma unroll 8
  for (int h = 0; h < 128; h += 2) {
    a0 = fmaf(softplusf_(fmaf(y, w1[h], b1[h])), w2[h], a0);
    a1 = fmaf(softplusf_(fmaf(y, w1[h + 1], b1[h + 1])), w2[h + 1], a1);
  }
  g_tab[gid] = sigmoidf_(a0 + a1 + gb2[l]);
}

// ---------------------------------------------------------------------------
// Kernel 2: backward GRU scan + encoder + qz0 head.
// 256 blocks x 512 threads, 2 batch/block.  *** ONE barrier per step ***:
// every wave redundantly applies the h-update (identical-value LDS writes;
// h_old carried in registers, deterministic across waves), then does its
// dot role.  Gates parity-buffered [p][g][b][du] (conflict-free writes);
// enc halves combined via shfl (pairs intra-wave), s_encp deleted.
// ---------------------------------------------------------------------------
__global__ __launch_bounds__(512) void k_gru(
    const f16* __restrict__ state_t, const float* __restrict__ wih,
    const float* __restrict__ whh, const float* __restrict__ bih,
    const float* __restrict__ bhh, const float* __restrict__ enc_w,
    const float* __restrict__ enc_b, const float* __restrict__ qz0_w,
    const float* __restrict__ qz0_b, const float* __restrict__ z0_noise,
    const float* __restrict__ pz0_mean, const float* __restrict__ pz0_logstd,
    f16* __restrict__ ctx, float* __restrict__ z0_out,
    float* __restrict__ accums) {
  __shared__ uint32_t s_x[2][2][16];   // [p][b] x_t, f16x2 packed
  __shared__ uint32_t s_h[2][64];      // [b] h, f16x2 packed
  __shared__ float s_g[2][4][2][128];  // [p][gate][b][du]
  __shared__ float s_ctx0[2][64];
  __shared__ float s_q[2][32];

  const int tid = threadIdx.x;
  const int ln = tid & 63;
  const int bbase = blockIdx.x * 2;
  const uint32_t* stu = (const uint32_t*)state_t;

  uint32_t wA[64];   // whh row (RZ/N) | enc half-row (32 used)
  uint32_t wB[16];   // wih row (RZ/N)
  float bias0 = 0.f, bias1 = 0.f, encbr = 0.f;

  if (tid < 256) {
    int g = tid >> 7, du = tid & 127;
    const float* whr = whh + (size_t)(g * 128 + du) * 128;
#pragma unroll
    for (int i = 0; i < 64; ++i) wA[i] = packh2(whr[2 * i], whr[2 * i + 1]);
    const float* wxr = wih + (size_t)(g * 128 + du) * 32;
#pragma unroll
    for (int i = 0; i < 16; ++i) wB[i] = packh2(wxr[2 * i], wxr[2 * i + 1]);
    bias0 = bih[g * 128 + du] + bhh[g * 128 + du];
  } else if (tid < 384) {
    int du = tid - 256;
    const float* whr = whh + (size_t)(256 + du) * 128;
#pragma unroll
    for (int i = 0; i < 64; ++i) wA[i] = packh2(whr[2 * i], whr[2 * i + 1]);
    const float* wxr = wih + (size_t)(256 + du) * 32;
#pragma unroll
    for (int i = 0; i < 16; ++i) wB[i] = packh2(wxr[2 * i], wxr[2 * i + 1]);
    bias0 = bih[256 + du];
    bias1 = bhh[256 + du];
  } else {
    int e = tid - 384, c = e >> 1, ks = e & 1;
    const float* wer = enc_w + (size_t)c * 128 + ks * 64;
#pragma unroll
    for (int i = 0; i < 32; ++i) wA[i] = packh2(wer[2 * i], wer[2 * i + 1]);
    encbr = enc_b[c];
  }

  float ho[2][2] = {{0.f, 0.f}, {0.f, 0.f}};  // h_old regs [b][j], du=2ln+j
  if (tid < 128) s_h[tid >> 6][tid & 63] = 0u;
  if (tid < 32) {
    int b = tid >> 4, i = tid & 15;
    s_x[1][b][i] = stu[((size_t)(T_STEPS - 1) * B_SZ + bbase + b) * 16 + i];
  }
  __syncthreads();

  for (int t = T_STEPS - 1; t >= 0; --t) {
    const int p = t & 1;
    uint4 xpref = make_uint4(0, 0, 0, 0);
    if (tid >= 368 && tid < 376 && t > 0) {
      int i = tid - 368, b = i & 1, q = i >> 1;
      xpref = *(const uint4*)(stu +
                              ((size_t)(t - 1) * B_SZ + bbase + b) * 16 + q * 4);
    }
    // ---- redundant h-update (all waves, identical values)
    if (t != T_STEPS - 1) {
#pragma unroll
      for (int b = 0; b < 2; ++b) {
        float2 G0 = *(const float2*)&s_g[p ^ 1][0][b][2 * ln];
        float2 G1 = *(const float2*)&s_g[p ^ 1][1][b][2 * ln];
        float2 G2 = *(const float2*)&s_g[p ^ 1][2][b][2 * ln];
        float2 G3 = *(const float2*)&s_g[p ^ 1][3][b][2 * ln];
        float r0 = sigmoidf_(G0.x), zg0 = sigmoidf_(G1.x);
        float n0 = tanhf_(G2.x + r0 * G3.x);
        float h0 = (1.0f - zg0) * n0 + zg0 * ho[b][0];
        ho[b][0] = h0;
        float r1 = sigmoidf_(G0.y), zg1 = sigmoidf_(G1.y);
        float n1 = tanhf_(G2.y + r1 * G3.y);
        float h1 = (1.0f - zg1) * n1 + zg1 * ho[b][1];
        ho[b][1] = h1;
        s_h[b][ln] = packh2(h0, h1);
      }
    }
    // ---- dots (own-wave DS order covers update->read; cross-wave identical)
    if (tid < 256) {
      int g = tid >> 7, du = tid & 127;
#pragma unroll
      for (int b = 0; b < 2; ++b) {
        float a0 = bias0, a1 = 0.f;
        const uint4* xq = (const uint4*)&s_x[p][b][0];
#pragma unroll
        for (int j = 0; j < 4; j += 2) {
          uint4 v0 = xq[j], v1 = xq[j + 1];
          DOT4(a0, wB[4 * j], wB[4 * j + 1], wB[4 * j + 2], wB[4 * j + 3], v0);
          DOT4(a1, wB[4 * j + 4], wB[4 * j + 5], wB[4 * j + 6], wB[4 * j + 7], v1);
        }
        const uint4* hq = (const uint4*)&s_h[b][0];
#pragma unroll
        for (int j = 0; j < 16; j += 2) {
          uint4 v0 = hq[j], v1 = hq[j + 1];
          DOT4(a0, wA[4 * j], wA[4 * j + 1], wA[4 * j + 2], wA[4 * j + 3], v0);
          DOT4(a1, wA[4 * j + 4], wA[4 * j + 5], wA[4 * j + 6], wA[4 * j + 7], v1);
        }
        s_g[p][g][b][du] = a0 + a1;
      }
    } else if (tid < 384) {
      int du = tid - 256;
#pragma unroll
      for (int b = 0; b < 2; ++b) {
        float aI = bias0, aH0 = bias1, aH1 = 0.f;
        const uint4* xq = (const uint4*)&s_x[p][b][0];
#pragma unroll
        for (int j = 0; j < 4; ++j) {
          uint4 v = xq[j];
          DOT4(aI, wB[4 * j], wB[4 * j + 1], wB[4 * j + 2], wB[4 * j + 3], v);
        }
        const uint4* hq = (const uint4*)&s_h[b][0];
#pragma unroll
        for (int j = 0; j < 16; j += 2) {
          uint4 v0 = hq[j], v1 = hq[j + 1];
          DOT4(aH0, wA[4 * j], wA[4 * j + 1], wA[4 * j + 2], wA[4 * j + 3], v0);
          DOT4(aH1, wA[4 * j + 4], wA[4 * j + 5], wA[4 * j + 6], wA[4 * j + 7], v1);
        }
        s_g[p][2][b][du] = aI;
        s_g[p][3][b][du] = aH0 + aH1;
      }
    } else {
      int e = tid - 384, c = e >> 1, ks = e & 1;
      (void)c;
      if (t < T_STEPS - 1) {
#pragma unroll
        for (int b = 0; b < 2; ++b) {
          float a0 = 0.f, a1 = 0.f;
          const uint4* hq = (const uint4*)&s_h[b][ks * 32];
#pragma unroll
          for (int j = 0; j < 8; j += 2) {
            uint4 v0 = hq[j], v1 = hq[j + 1];
            DOT4(a0, wA[4 * j], wA[4 * j + 1], wA[4 * j + 2], wA[4 * j + 3], v0);
            DOT4(a1, wA[4 * j + 4], wA[4 * j + 5], wA[4 * j + 6], wA[4 * j + 7], v1);
          }
          float a = a0 + a1;
          float full = a + __shfl_xor(a, 1);
          if (ks == 0)
            ctx[((size_t)(t + 1) * B_SZ + bbase + b) * 64 + c] =
                (f16)(full + encbr);
        }
      }
    }
    if (tid >= 368 && tid < 376 && t > 0) {
      int i = tid - 368, b = i & 1, q = i >> 1;
      *(uint4*)&s_x[p ^ 1][b][q * 4] = xpref;
    }
    barrier_lds();
  }

  // ---- Tail: final h-update (gates(0) in s_g[0]) -> h(0); enc; qz0; z0+KL
  {
#pragma unroll
    for (int b = 0; b < 2; ++b) {
      float2 G0 = *(const float2*)&s_g[0][0][b][2 * ln];
      float2 G1 = *(const float2*)&s_g[0][1][b][2 * ln];
      float2 G2 = *(const float2*)&s_g[0][2][b][2 * ln];
      float2 G3 = *(const float2*)&s_g[0][3][b][2 * ln];
      float r0 = sigmoidf_(G0.x), zg0 = sigmoidf_(G1.x);
      float n0 = tanhf_(G2.x + r0 * G3.x);
      float h0 = (1.0f - zg0) * n0 + zg0 * ho[b][0];
      float r1 = sigmoidf_(G0.y), zg1 = sigmoidf_(G1.y);
      float n1 = tanhf_(G2.y + r1 * G3.y);
      float h1 = (1.0f - zg1) * n1 + zg1 * ho[b][1];
      s_h[b][ln] = packh2(h0, h1);
    }
  }
  __syncthreads();
  if (tid >= 384) {
    int e = tid - 384, c = e >> 1, ks = e & 1;
#pragma unroll
    for (int b = 0; b < 2; ++b) {
      float a0 = 0.f, a1 = 0.f;
      const uint4* hq = (const uint4*)&s_h[b][ks * 32];
#pragma unroll
      for (int j = 0; j < 8; j += 2) {
        uint4 v0 = hq[j], v1 = hq[j + 1];
        DOT4(a0, wA[4 * j], wA[4 * j + 1], wA[4 * j + 2], wA[4 * j + 3], v0);
        DOT4(a1, wA[4 * j + 4], wA[4 * j + 5], wA[4 * j + 6], wA[4 * j + 7], v1);
      }
      float a = a0 + a1;
      float full = a + __shfl_xor(a, 1);
      if (ks == 0) {
        float val = full + encbr;
        ctx[((size_t)bbase + b) * 64 + c] = (f16)val;
        s_ctx0[b][c] = val;
      }
    }
  }
  __syncthreads();
  if (tid < 64) {
    int b = tid >> 5, o = tid & 31;
    float acc = qz0_b[o];
#pragma unroll 8
    for (int k = 0; k < 64; ++k) acc += qz0_w[o * 64 + k] * s_ctx0[b][k];
    s_q[b][o] = acc;
  }
  __syncthreads();
  if (tid < 32) {
    int b = tid >> 4, l = tid & 15;
    int bg = bbase + b;
    float qm = s_q[b][l], qls = s_q[b][16 + l];
    float z0v = qm + __expf(qls) * z0_noise[bg * 16 + l];
    z0_out[bg * 16 + l] = z0v;
    float pm = pz0_mean[l], pls = pz0_logstd[l];
    float var_q = __expf(2.0f * qls);
    float var_p = __expf(2.0f * pls);
    float dm = qm - pm;
    float kl = pls - qls + (var_q + dm * dm) / (2.0f * var_p) - 0.5f;
    atomicAdd(&accums[5], kl);
  }
}

// ---------------------------------------------------------------------------
// Kernel 3: SDE scan.  512 blocks x 256 threads, 1 batch/block, 2 blocks/CU.
// *** TWO barriers/step ***:
//   Phase A: L3(t-1) redundantly per wave (weights in LDS) -> shfl combine
//            -> z-update redundantly on 16 lanes/wave (identical-value z
//            write) -> L1(t) as shfl-paired half-rows.
//   Phase B: L2 full rows.
// g-table / bm / ctx prefetches retain one-phase latency slack.
// ---------------------------------------------------------------------------
__global__ __launch_bounds__(256, 2) void k_sde(
    const f16* __restrict__ ctx, const float* __restrict__ z0_in,
    const float* __restrict__ ts, const float* __restrict__ bm_noise,
    const float* __restrict__ fw1, const float* __restrict__ fb1,
    const float* __restrict__ fw2, const float* __restrict__ fb2,
    const float* __restrict__ fw3, const float* __restrict__ fb3,
    const float* __restrict__ hw1, const float* __restrict__ hb1,
    const float* __restrict__ hw2, const float* __restrict__ hb2,
    const float* __restrict__ hw3, const float* __restrict__ hb3,
    const float* __restrict__ g_tab,
    f16* __restrict__ zs, float* __restrict__ accums) {
  __shared__ uint32_t s_x2[2][40];   // [p][ z(8 u32) | ctx(32 u32) ]
  __shared__ uint32_t s_h1[2][64];   // [mlp] layer-1 act
  __shared__ uint32_t s_h2[2][64];   // [mlp] layer-2 act
  __shared__ uint4 s_w3[8][64];      // L3 weights, lane-interleaved
  __shared__ float s_dts[T_STEPS];

  const int tid = threadIdx.x;
  const int lane = tid & 63;
  const int bg = blockIdx.x;
  const uint4* ctx4 = (const uint4*)ctx;

  // role indices
  const int r1 = tid >> 1, hh = tid & 1;            // L1 half-rows
  const int mlp = tid >> 7, u2 = tid & 127;         // L2
  const int r3 = lane >> 1;                         // L3: 0..31
  const int net3 = r3 >> 4;                         // 0=f3, 1=h3
  const int l3 = r3 & 15;
  const int hh3 = lane & 1;
  const bool zlane = (net3 == 0) && (hh3 == 0);     // lane = 2*l3
  const bool stg = (tid >= 32 && tid < 40);         // ctx stagers (wave0)

  // ---- weight preload
  uint32_t uw1f[20], uw1h[4], wP2[64];
  float bf1r, bh1r, bias2r, fb3r, hb3r;
  {
    const float* w = fw1 + (size_t)r1 * 80 + hh * 40;
#pragma unroll
    for (int i = 0; i < 20; ++i) uw1f[i] = packh2(w[2 * i], w[2 * i + 1]);
    bf1r = fb1[r1];
  }
  {
    const float* w = hw1 + (size_t)r1 * 16 + hh * 8;
#pragma unroll
    for (int i = 0; i < 4; ++i) uw1h[i] = packh2(w[2 * i], w[2 * i + 1]);
    bh1r = hb1[r1];
  }
  {
    const float* w = (mlp ? hw2 : fw2) + (size_t)u2 * 128;
#pragma unroll
    for (int i = 0; i < 64; ++i) wP2[i] = packh2(w[2 * i], w[2 * i + 1]);
    bias2r = (mlp ? hb2 : fb2)[u2];
  }
  fb3r = fb3[l3];
  hb3r = hb3[l3];
  if (tid < 64) {
    const float* w = (net3 ? hw3 : fw3) + (size_t)l3 * 128 + hh3 * 64;
#pragma unroll
    for (int j = 0; j < 8; ++j) {
      uint4 q;
      q.x = packh2(w[8 * j + 0], w[8 * j + 1]);
      q.y = packh2(w[8 * j + 2], w[8 * j + 3]);
      q.z = packh2(w[8 * j + 4], w[8 * j + 5]);
      q.w = packh2(w[8 * j + 6], w[8 * j + 7]);
      s_w3[j][tid] = q;
    }
  }
  for (int i = tid; i < T_STEPS - 1; i += 256) s_dts[i] = ts[i + 1] - ts[i];

  // ---- state init
  float zreg = 0.f, bmc = 0.f, bmn = 0.f, gvp = 0.f, path_acc = 0.f;
  uint4 cpref = make_uint4(0, 0, 0, 0);
  if (zlane) {
    zreg = z0_in[bg * 16 + l3];
    ((f16*)&s_x2[0][0])[l3] = (f16)zreg;
    if (tid < 64) zs[(size_t)bg * 16 + l3] = (f16)zreg;
    bmc = bm_noise[(size_t)bg * 16 + l3];                       // bm[0]
    bmn = bm_noise[((size_t)1 * B_SZ + bg) * 16 + l3];          // bm[1]
    unsigned short zb = __builtin_bit_cast(unsigned short, (f16)zreg);
    gvp = g_tab[l3 * 65536 + (int)zb];
  }
  if (stg) {
    int q = tid - 32;
    uint4 v = ctx4[((size_t)1 * B_SZ + bg) * 8 + q];
    *(uint4*)&s_x2[0][8 + q * 4] = v;
  }
  __syncthreads();

  for (int t = 0; t < T_STEPS - 1; ++t) {
    const int p = t & 1;
    if (stg && t <= T_STEPS - 3)
      cpref = ctx4[((size_t)(t + 2) * B_SZ + bg) * 8 + (tid - 32)];
    // ---- Phase A part 1: L3(t-1) + z-update (redundant per wave)
    if (t > 0) {
      const uint4* hq = (const uint4*)&s_h2[net3][hh3 * 32];
      float a0 = 0.f, a1 = 0.f;
#pragma unroll
      for (int j = 0; j < 8; j += 2) {
        uint4 w0 = s_w3[j][lane], w1v = s_w3[j + 1][lane];
        uint4 v0 = hq[j], v1 = hq[j + 1];
        DOT4(a0, w0.x, w0.y, w0.z, w0.w, v0);
        DOT4(a1, w1v.x, w1v.y, w1v.z, w1v.w, v1);
      }
      float a = a0 + a1;
      float full = a + __shfl_xor(a, 1);    // combine 64-wide halves
      float cross = __shfl_xor(full, 32);   // f <-> h rows (same l3)
      if (zlane) {
        float fv = full + fb3r;
        float hv = cross + hb3r;
        float gv = gvp;
        float dt = s_dts[t - 1];
        float u_ = (fv - hv) / gv;
        float ls = u_ * u_;
        ls += __shfl_xor(ls, 2);
        ls += __shfl_xor(ls, 4);
        ls += __shfl_xor(ls, 8);
        ls += __shfl_xor(ls, 16);
        if (tid == 0) path_acc += 0.5f * ls * dt;
        float dw = sqrtf(dt) * bmc;
        float zn = zreg + fv * dt + gv * dw;
        zreg = zn;
        ((f16*)&s_x2[p][0])[l3] = (f16)zn;   // identical across waves
        if (tid < 64) zs[((size_t)t * B_SZ + bg) * 16 + l3] = (f16)zn;
        bmc = bmn;
        if (t <= T_STEPS - 3)
          bmn = bm_noise[((size_t)(t + 1) * B_SZ + bg) * 16 + l3];
        unsigned short zb = __builtin_bit_cast(unsigned short, (f16)zn);
        gvp = g_tab[l3 * 65536 + (int)zb];
      }
    }
    // ---- Phase A part 2: L1(t) half-rows
    {
      const uint4* xq = (const uint4*)&s_x2[p][0];
      const int base = hh * 5;
      float a0 = 0.f, a1 = 0.f;
      {
        uint4 v0 = xq[base + 0], v1 = xq[base + 1];
        DOT4(a0, uw1f[0], uw1f[1], uw1f[2], uw1f[3], v0);
        DOT4(a1, uw1f[4], uw1f[5], uw1f[6], uw1f[7], v1);
        uint4 v2 = xq[base + 2], v3 = xq[base + 3];
        DOT4(a0, uw1f[8], uw1f[9], uw1f[10], uw1f[11], v2);
        DOT4(a1, uw1f[12], uw1f[13], uw1f[14], uw1f[15], v3);
        uint4 v4 = xq[base + 4];
        DOT4(a0, uw1f[16], uw1f[17], uw1f[18], uw1f[19], v4);
      }
      float af = a0 + a1;
      uint4 vz = xq[hh];
      float ah = 0.f;
      DOT4(ah, uw1h[0], uw1h[1], uw1h[2], uw1h[3], vz);
      float ff = af + __shfl_xor(af, 1);
      float fh = ah + __shfl_xor(ah, 1);
      if (hh == 0)
        ((f16*)&s_h1[0][0])[r1] = (f16)softplusf_(ff + bf1r);
      else
        ((f16*)&s_h1[1][0])[r1] = (f16)softplusf_(fh + bh1r);
    }
    barrier_lds();
    // ---- Phase B: L2 full rows
    {
      const uint4* hq = (const uint4*)&s_h1[mlp][0];
      float a0 = 0.f, a1 = 0.f;
#pragma unroll
      for (int j = 0; j < 16; j += 2) {
        uint4 v0 = hq[j], v1 = hq[j + 1];
        DOT4(a0, wP2[4 * j], wP2[4 * j + 1], wP2[4 * j + 2], wP2[4 * j + 3], v0);
        DOT4(a1, wP2[4 * j + 4], wP2[4 * j + 5], wP2[4 * j + 6], wP2[4 * j + 7], v1);
      }
      ((f16*)&s_h2[mlp][0])[u2] = (f16)softplusf_(a0 + a1 + bias2r);
    }
    if (stg && t <= T_STEPS - 3)
      *(uint4*)&s_x2[p ^ 1][8 + (tid - 32) * 4] = cpref;
    barrier_lds();
  }

  // ---- Tail: L3(510) -> z(511) (wave0 only)
  if (tid < 64) {
    const uint4* hq = (const uint4*)&s_h2[net3][hh3 * 32];
    float a0 = 0.f, a1 = 0.f;
#pragma unroll
    for (int j = 0; j < 8; j += 2) {
      uint4 w0 = s_w3[j][lane], w1v = s_w3[j + 1][lane];
      uint4 v0 = hq[j], v1 = hq[j + 1];
      DOT4(a0, w0.x, w0.y, w0.z, w0.w, v0);
      DOT4(a1, w1v.x, w1v.y, w1v.z, w1v.w, v1);
    }
    float a = a0 + a1;
    float full = a + __shfl_xor(a, 1);
    float cross = __shfl_xor(full, 32);
    if (zlane) {
      float fv = full + fb3r;
      float hv = cross + hb3r;
      float gv = gvp;
      float dt = s_dts[T_STEPS - 2];
      float u_ = (fv - hv) / gv;
      float ls = u_ * u_;
      ls += __shfl_xor(ls, 2);
      ls += __shfl_xor(ls, 4);
      ls += __shfl_xor(ls, 8);
      ls += __shfl_xor(ls, 16);
      if (tid == 0) path_acc += 0.5f * ls * dt;
      float dw = sqrtf(dt) * bmc;
      float zn = zreg + fv * dt + gv * dw;
      zs[((size_t)(T_STEPS - 1) * B_SZ + bg) * 16 + l3] = (f16)zn;
    }
  }
  if (tid == 0) atomicAdd(&accums[6], path_acc);
}

// ---------------------------------------------------------------------------
// Kernel 4: decoder + losses.  One thread per (t,b).
// ---------------------------------------------------------------------------
__global__ __launch_bounds__(256) void k_dec(
    const f16* __restrict__ zs, const f16* __restrict__ state_t,
    const float* __restrict__ xs, const float* __restrict__ proj_w,
    const float* __restrict__ proj_b, const float* __restrict__ act_w,
    const float* __restrict__ act_b, const float* __restrict__ land_w,
    const float* __restrict__ shot_w, const float* __restrict__ move_w,
    float* __restrict__ accums) {
  __shared__ uint32_t s_proj[8 * 32];
  __shared__ uint32_t s_act[8 * 128];
  __shared__ uint32_t s_head[128 * 8];
  __shared__ float s_pb[32], s_ab[128];
  __shared__ float s_red[4 * 5];

  const int tid = threadIdx.x;
  for (int id = tid; id < 8 * 32; id += 256) {
    int kp = id & 7, n = id >> 3;
    s_proj[kp * 32 + n] = packh2(proj_w[n * 16 + 2 * kp], proj_w[n * 16 + 2 * kp + 1]);
  }
  for (int id = tid; id < 8 * 128; id += 256) {
    int kp = id & 7, n = id >> 3;
    s_act[kp * 128 + n] = packh2(act_w[n * 16 + 2 * kp], act_w[n * 16 + 2 * kp + 1]);
  }
  for (int id = tid; id < 128 * 8; id += 256) {
    int j = id >> 3, p = id & 7;
    int h0 = 2 * p, h1 = 2 * p + 1;
    float w0 = (h0 < 2) ? land_w[h0 * 128 + j]
                        : (h0 < 14 ? shot_w[(h0 - 2) * 128 + j]
                                   : move_w[(h0 - 14) * 128 + j]);
    float w1 = (h1 < 2) ? land_w[h1 * 128 + j]
                        : (h1 < 14 ? shot_w[(h1 - 2) * 128 + j]
                                   : move_w[(h1 - 14) * 128 + j]);
    s_head[j * 8 + p] = packh2(w0, w1);
  }
  if (tid < 32) s_pb[tid] = proj_b[tid];
  if (tid < 128) s_ab[tid] = act_b[tid];
  __syncthreads();

  size_t idx = (size_t)blockIdx.x * 256 + tid;
  uint32_t z2[8];
  const uint32_t* zp = (const uint32_t*)(zs + idx * 16);
#pragma unroll
  for (int i = 0; i < 8; ++i) z2[i] = zp[i];
  uint32_t stv[16];
  const uint32_t* stp = (const uint32_t*)(state_t + idx * 32);
#pragma unroll
  for (int i = 0; i < 16; ++i) stv[i] = stp[i];

  float sqsum = 0.0f;
#pragma unroll 4
  for (int i = 0; i < 32; ++i) {
    float acc = s_pb[i];
#pragma unroll
    for (int kp = 0; kp < 8; ++kp) acc = fdot2(s_proj[kp * 32 + i], z2[kp], acc);
    f16x2 sv = __builtin_bit_cast(f16x2, stv[i >> 1]);
    float d = (float)sv[i & 1] - acc;
    sqsum += d * d;
  }

  float hd[16];
#pragma unroll
  for (int i = 0; i < 16; ++i) hd[i] = 0.0f;
#pragma unroll 2
  for (int j = 0; j < 128; ++j) {
    float a = s_ab[j];
#pragma unroll
    for (int kp = 0; kp < 8; ++kp) a = fdot2(s_act[kp * 128 + j], z2[kp], a);
    a = fmaxf(a, 0.0f);
#pragma unroll
    for (int p = 0; p < 8; ++p) {
      f16x2 w = __builtin_bit_cast(f16x2, s_head[j * 8 + p]);
      hd[2 * p] += (float)w[0] * a;
      hd[2 * p + 1] += (float)w[1] * a;
    }
  }
  const float* xp = xs + idx * 23;
  float dl0 = hd[0] - xp[18], dl1 = hd[1] - xp[19];
  float land = dl0 * dl0 + dl1 * dl1;
  float dm0 = hd[14] - xp[21], dm1 = hd[15] - xp[22];
  float move = dm0 * dm0 + dm1 * dm1;
  int sid = (int)xp[20];
  float m = hd[2];
#pragma unroll
  for (int s = 1; s < 12; ++s) m = fmaxf(m, hd[2 + s]);
  float sume = 0.0f;
#pragma unroll
  for (int s = 0; s < 12; ++s) sume += __expf(hd[2 + s] - m);
  float lse = m + __logf(sume);
  float pl = 0.0f;
#pragma unroll
  for (int s = 0; s < 12; ++s)
    if (s == sid) pl = hd[2 + s];
  float picked = 0.0f, cnt = 0.0f;
  if (sid != 0) {
    picked = pl - lse;
    cnt = 1.0f;
  }
  float vals[5] = {sqsum, land, move, picked, cnt};
#pragma unroll
  for (int v = 0; v < 5; ++v) {
    float x = vals[v];
    for (int off = 1; off < 64; off <<= 1) x += __shfl_xor(x, off);
    vals[v] = x;
  }
  int lane = tid & 63, wv = tid >> 6;
  if (lane == 0) {
#pragma unroll
    for (int v = 0; v < 5; ++v) s_red[wv * 5 + v] = vals[v];
  }
  __syncthreads();
  if (tid == 0) {
#pragma unroll
    for (int v = 0; v < 5; ++v) {
      float s = s_red[v] + s_red[5 + v] + s_red[10 + v] + s_red[15 + v];
      atomicAdd(&accums[v], s);
    }
  }
}

// ---------------------------------------------------------------------------
// Kernel 5: finalize the two scalar outputs.
// ---------------------------------------------------------------------------
__global__ void k_fin(const float* __restrict__ accums,
                      const float* __restrict__ noise_std,
                      float* __restrict__ out) {
  if (threadIdx.x == 0 && blockIdx.x == 0) {
    float sd = noise_std[0];
    float log_pxs = -0.5f * accums[0] / (sd * sd * (float)B_SZ) -
                    (float)T_STEPS * 32.0f * (logf(sd) + 0.5f * LOG2PI);
    float land = accums[1] / (float)(T_STEPS * B_SZ * 2);
    float move = accums[2] / (float)(T_STEPS * B_SZ * 2);
    float shot = -accums[3] / fmaxf(accums[4], 1.0f);
    float out1 = accums[5] / (float)B_SZ + accums[6] / (float)B_SZ + land + shot + move;
    out[0] = log_pxs;
    out[1] = out1;
  }
}

// ---------------------------------------------------------------------------
extern "C" void kernel_launch(void* const* d_in, const int* in_sizes, int n_in,
                              void* d_out, int out_size, void* d_ws,
                              size_t ws_size, hipStream_t stream) {
  const float* xs = (const float*)d_in[1];
  const float* ts = (const float*)d_in[2];
  const float* noise_std = (const float*)d_in[3];
  const float* z0_noise = (const float*)d_in[4];
  const float* bm_noise = (const float*)d_in[5];
  const float* shot_emb = (const float*)d_in[6];
  const float* player_emb = (const float*)d_in[7];
  const float* gru_wih = (const float*)d_in[8];
  const float* gru_whh = (const float*)d_in[9];
  const float* gru_bih = (const float*)d_in[10];
  const float* gru_bhh = (const float*)d_in[11];
  const float* enc_w = (const float*)d_in[12];
  const float* enc_b = (const float*)d_in[13];
  const float* qz0_w = (const float*)d_in[14];
  const float* qz0_b = (const float*)d_in[15];
  const float* f_w1 = (const float*)d_in[16];
  const float* f_b1 = (const float*)d_in[17];
  const float* f_w2 = (const float*)d_in[18];
  const float* f_b2 = (const float*)d_in[19];
  const float* f_w3 = (const float*)d_in[20];
  const float* f_b3 = (const float*)d_in[21];
  const float* h_w1 = (const float*)d_in[22];
  const float* h_b1 = (const float*)d_in[23];
  const float* h_w2 = (const float*)d_in[24];
  const float* h_b2 = (const float*)d_in[25];
  const float* h_w3 = (const float*)d_in[26];
  const float* h_b3 = (const float*)d_in[27];
  const float* g_w1 = (const float*)d_in[28];
  const float* g_b1 = (const float*)d_in[29];
  const float* g_w2 = (const float*)d_in[30];
  const float* g_b2 = (const float*)d_in[31];
  const float* proj_w = (const float*)d_in[32];
  const float* proj_b = (const float*)d_in[33];
  const float* pz0_mean = (const float*)d_in[34];
  const float* pz0_logstd = (const float*)d_in[35];
  const float* act_w = (const float*)d_in[36];
  const float* act_b = (const float*)d_in[37];
  const float* act_land_w = (const float*)d_in[38];
  const float* act_shot_w = (const float*)d_in[39];
  const float* act_move_w = (const float*)d_in[40];

  char* ws = (char*)d_ws;
  float* accums = (float*)ws;                       // 16 floats (256 B reserved)
  f16* state_t = (f16*)(ws + 256);                  // T*B*32 f16 = 16 MB
  f16* ctx = (f16*)(ws + 256 + 16777216);           // T*B*64 f16 = 32 MB
  float* z0b = (float*)(ws + 256 + 16777216 + 33554432);   // B*16 f32
  f16* zs = (f16*)(ws + 256 + 16777216 + 33554432 + 32768);  // T*B*16 f16 = 8 MB
  float* g_tab = (float*)(ws + 256 + 16777216 + 33554432 + 32768 + 8388608);  // 4 MB

  k_embed<<<1024, 256, 0, stream>>>(xs, shot_emb, player_emb, state_t, accums);
  k_gtab<<<4096, 256, 0, stream>>>(g_w1, g_b1, g_w2, g_b2, g_tab);
  k_gru<<<256, 512, 0, stream>>>(state_t, gru_wih, gru_whh, gru_bih, gru_bhh,
                                 enc_w, enc_b, qz0_w, qz0_b, z0_noise, pz0_mean,
                                 pz0_logstd, ctx, z0b, accums);
  k_sde<<<512, 256, 0, stream>>>(ctx, z0b, ts, bm_noise, f_w1, f_b1, f_w2, f_b2,
                                 f_w3, f_b3, h_w1, h_b1, h_w2, h_b2, h_w3, h_b3,
                                 g_tab, zs, accums);
  k_dec<<<1024, 256, 0, stream>>>(zs, state_t, xs, proj_w, proj_b, act_w, act_b,
                                  act_land_w, act_shot_w, act_move_w, accums);
  k_fin<<<1, 64, 0, stream>>>(accums, noise_std, (float*)d_out);
}

// Round 9
// 1737.121 us; speedup vs baseline: 1.2653x; 1.2653x over previous
//
#include <hip/hip_runtime.h>
#include <cstdint>

typedef _Float16 f16;
typedef _Float16 f16x2 __attribute__((ext_vector_type(2)));

#define T_STEPS 512
#define B_SZ 512
#define LOG2PI 1.8378770664093453f

// Raw barrier: drain LDS only (NOT vmcnt) so in-flight global prefetch loads
// and stores survive across the barrier.
__device__ __forceinline__ void barrier_lds() {
  asm volatile("s_waitcnt lgkmcnt(0)" ::: "memory");
  __builtin_amdgcn_s_barrier();
  asm volatile("" ::: "memory");
}

__device__ __forceinline__ uint32_t packh2(float a, float b) {
  f16x2 v; v[0] = (f16)a; v[1] = (f16)b;
  return __builtin_bit_cast(uint32_t, v);
}

__device__ __forceinline__ float fdot2(uint32_t a, uint32_t b, float c) {
#if defined(__AMDGCN__) && __has_builtin(__builtin_amdgcn_fdot2)
  return __builtin_amdgcn_fdot2(__builtin_bit_cast(f16x2, a),
                                __builtin_bit_cast(f16x2, b), c, false);
#else
  f16x2 x = __builtin_bit_cast(f16x2, a), y = __builtin_bit_cast(f16x2, b);
  return c + (float)x[0] * (float)y[0] + (float)x[1] * (float)y[1];
#endif
}

#define DOT4(acc, w0, w1, w2, w3, v)                                     \
  do {                                                                   \
    acc = fdot2((w0), (v).x, acc); acc = fdot2((w1), (v).y, acc);        \
    acc = fdot2((w2), (v).z, acc); acc = fdot2((w3), (v).w, acc);        \
  } while (0)

__device__ __forceinline__ float sigmoidf_(float x) {
  return 1.0f / (1.0f + __expf(-x));
}
__device__ __forceinline__ float tanhf_(float x) {
  float ax = fabsf(x);
  float t = __expf(-2.0f * ax);
  float r = (1.0f - t) / (1.0f + t);
  return copysignf(r, x);
}
__device__ __forceinline__ float softplusf_(float x) {
  return fmaxf(x, 0.0f) + __logf(1.0f + __expf(-fabsf(x)));
}

// ---------------------------------------------------------------------------
// Kernel 1: embedding / state_t construction.  state_t: (T,B,32) f16.
// ---------------------------------------------------------------------------
__global__ __launch_bounds__(256) void k_embed(
    const float* __restrict__ xs, const float* __restrict__ shot_emb,
    const float* __restrict__ player_emb, f16* __restrict__ state_t,
    float* __restrict__ accums) {
  if (blockIdx.x == 0 && threadIdx.x < 16) accums[threadIdx.x] = 0.0f;
  size_t idx = (size_t)blockIdx.x * 256 + threadIdx.x;
  const float* xp = xs + idx * 23;
  f16* op = state_t + idx * 32;
  int sid = (int)xp[12];
  int pid = (int)xp[17];
#pragma unroll
  for (int i = 0; i < 12; ++i) op[i] = (f16)xp[i];
  const float* se = shot_emb + sid * 8;
#pragma unroll
  for (int i = 0; i < 8; ++i) op[12 + i] = (f16)se[i];
#pragma unroll
  for (int i = 0; i < 4; ++i) op[20 + i] = (f16)xp[13 + i];
  const float* pe = player_emb + pid * 8;
#pragma unroll
  for (int i = 0; i < 8; ++i) op[24 + i] = (f16)pe[i];
}

// ---------------------------------------------------------------------------
// Kernel 1b: g-network lookup table (R6-verified).  16 x 65536 f32 = 4 MB.
// ---------------------------------------------------------------------------
__global__ __launch_bounds__(256) void k_gtab(
    const float* __restrict__ gw1, const float* __restrict__ gb1,
    const float* __restrict__ gw2, const float* __restrict__ gb2,
    float* __restrict__ g_tab) {
  int gid = blockIdx.x * 256 + threadIdx.x;
  int l = gid >> 16, yi = gid & 0xffff;
  f16 hy = __builtin_bit_cast(f16, (unsigned short)yi);
  float y = (float)hy;
  const float* w1 = gw1 + l * 128;
  const float* b1 = gb1 + l * 128;
  const float* w2 = gw2 + l * 128;
  float a0 = 0.f, a1 = 0.f;
#pragma unroll 8
  for (int h = 0; h < 128; h += 2) {
    a0 = fmaf(softplusf_(fmaf(y, w1[h], b1[h])), w2[h], a0);
    a1 = fmaf(softplusf_(fmaf(y, w1[h + 1], b1[h + 1])), w2[h + 1], a1);
  }
  g_tab[gid] = sigmoidf_(a0 + a1 + gb2[l]);
}

// ---------------------------------------------------------------------------
// Kernel 2: backward GRU scan + encoder + qz0 head.  (R7-bench verified)
// 256 blocks x 512 threads, 2 batch/block.  2 LDS-only barriers/step.
// ---------------------------------------------------------------------------
__global__ __launch_bounds__(512) void k_gru(
    const f16* __restrict__ state_t, const float* __restrict__ wih,
    const float* __restrict__ whh, const float* __restrict__ bih,
    const float* __restrict__ bhh, const float* __restrict__ enc_w,
    const float* __restrict__ enc_b, const float* __restrict__ qz0_w,
    const float* __restrict__ qz0_b, const float* __restrict__ z0_noise,
    const float* __restrict__ pz0_mean, const float* __restrict__ pz0_logstd,
    f16* __restrict__ ctx, float* __restrict__ z0_out,
    float* __restrict__ accums) {
  __shared__ uint32_t s_x[2][16];      // x_t, f16x2 packed
  __shared__ uint32_t s_h[2][64];      // h,   f16x2 packed
  __shared__ float s_gates[2 * 128 * 4];  // [b][du][R,Z,iN,hN]
  __shared__ float s_encp[2 * 64 * 2];    // [b][c][ks]
  __shared__ float s_ctx0[2][64];
  __shared__ float s_q[2][32];

  const int tid = threadIdx.x;
  const int bbase = blockIdx.x * 2;
  const uint32_t* stu = (const uint32_t*)state_t;

  uint32_t wA[64];   // whh row (RZ/N) | enc half-row (enc, 32 used)
  uint32_t wB[16];   // wih row (RZ/N)
  float bias0 = 0.f, bias1 = 0.f, encbr = 0.f;

  if (tid < 256) {
    int g = tid >> 7, du = tid & 127;
    const float* whr = whh + (size_t)(g * 128 + du) * 128;
#pragma unroll
    for (int i = 0; i < 64; ++i) wA[i] = packh2(whr[2 * i], whr[2 * i + 1]);
    const float* wxr = wih + (size_t)(g * 128 + du) * 32;
#pragma unroll
    for (int i = 0; i < 16; ++i) wB[i] = packh2(wxr[2 * i], wxr[2 * i + 1]);
    bias0 = bih[g * 128 + du] + bhh[g * 128 + du];
  } else if (tid < 384) {
    int du = tid - 256;
    const float* whr = whh + (size_t)(256 + du) * 128;
#pragma unroll
    for (int i = 0; i < 64; ++i) wA[i] = packh2(whr[2 * i], whr[2 * i + 1]);
    const float* wxr = wih + (size_t)(256 + du) * 32;
#pragma unroll
    for (int i = 0; i < 16; ++i) wB[i] = packh2(wxr[2 * i], wxr[2 * i + 1]);
    bias0 = bih[256 + du];
    bias1 = bhh[256 + du];
  } else {
    int e = tid - 384, c = e & 63, ks = e >> 6;
    const float* wer = enc_w + (size_t)c * 128 + ks * 64;
#pragma unroll
    for (int i = 0; i < 32; ++i) wA[i] = packh2(wer[2 * i], wer[2 * i + 1]);
    encbr = enc_b[c];
  }

  if (tid < 128) s_h[tid >> 6][tid & 63] = 0u;
  if (tid < 32) {
    int b = tid >> 4, i = tid & 15;
    s_x[b][i] = stu[((size_t)(T_STEPS - 1) * B_SZ + bbase + b) * 16 + i];
  }
  float h_old = 0.0f;
  __syncthreads();

  for (int t = T_STEPS - 1; t >= 0; --t) {
    uint4 xpref = make_uint4(0, 0, 0, 0);
    // ---- Phase A: gate dots (R/Z/N) + enc dots for h(t+1) + x prefetch
    if (tid < 256) {
      int g = tid >> 7, du = tid & 127;
#pragma unroll
      for (int b = 0; b < 2; ++b) {
        float a = bias0;
        const uint4* xq = (const uint4*)&s_x[b][0];
#pragma unroll
        for (int j = 0; j < 4; ++j) {
          uint4 v = xq[j];
          DOT4(a, wB[4 * j], wB[4 * j + 1], wB[4 * j + 2], wB[4 * j + 3], v);
        }
        const uint4* hq = (const uint4*)&s_h[b][0];
#pragma unroll
        for (int j = 0; j < 16; ++j) {
          uint4 v = hq[j];
          DOT4(a, wA[4 * j], wA[4 * j + 1], wA[4 * j + 2], wA[4 * j + 3], v);
        }
        s_gates[(b * 128 + du) * 4 + g] = a;
      }
    } else if (tid < 384) {
      int du = tid - 256;
#pragma unroll
      for (int b = 0; b < 2; ++b) {
        float aI = bias0, aH = bias1;
        const uint4* xq = (const uint4*)&s_x[b][0];
#pragma unroll
        for (int j = 0; j < 4; ++j) {
          uint4 v = xq[j];
          DOT4(aI, wB[4 * j], wB[4 * j + 1], wB[4 * j + 2], wB[4 * j + 3], v);
        }
        const uint4* hq = (const uint4*)&s_h[b][0];
#pragma unroll
        for (int j = 0; j < 16; ++j) {
          uint4 v = hq[j];
          DOT4(aH, wA[4 * j], wA[4 * j + 1], wA[4 * j + 2], wA[4 * j + 3], v);
        }
        s_gates[(b * 128 + du) * 4 + 2] = aI;
        s_gates[(b * 128 + du) * 4 + 3] = aH;
      }
    } else {
      int e = tid - 384, ks = e >> 6, cc = e & 63;
      (void)cc;
      if (t < T_STEPS - 1) {
#pragma unroll
        for (int b = 0; b < 2; ++b) {
          float a = 0.f;
          const uint4* hq = (const uint4*)&s_h[b][ks * 32];
#pragma unroll
          for (int j = 0; j < 8; ++j) {
            uint4 v = hq[j];
            DOT4(a, wA[4 * j], wA[4 * j + 1], wA[4 * j + 2], wA[4 * j + 3], v);
          }
          s_encp[(b * 64 + cc) * 2 + ks] = a;
        }
      }
      if (e < 8 && t > 0) {
        int b = e & 1, q = e >> 1;
        xpref = *(const uint4*)(stu +
                                ((size_t)(t - 1) * B_SZ + bbase + b) * 16 + q * 4);
      }
    }
    barrier_lds();
    // ---- Phase B: h update; ctx combine; x stage
    if (tid < 256) {
      int b = tid >> 7, du = tid & 127;
      const float4 gt = *(const float4*)&s_gates[(b * 128 + du) * 4];
      float r = sigmoidf_(gt.x), zg = sigmoidf_(gt.y);
      float n = tanhf_(gt.z + r * gt.w);
      float hnew = (1.0f - zg) * n + zg * h_old;
      h_old = hnew;
      ((f16*)&s_h[b][0])[du] = (f16)hnew;
    } else if (tid >= 384) {
      int e = tid - 384, cc = e & 63, b = e >> 6;
      if (t < T_STEPS - 1) {
        float2 p = *(const float2*)&s_encp[(b * 64 + cc) * 2];
        ctx[((size_t)(t + 1) * B_SZ + bbase + b) * 64 + cc] =
            (f16)(p.x + p.y + encbr);
      }
      if (e < 8 && t > 0) {
        int b2 = e & 1, q = e >> 1;
        *(uint4*)&s_x[b2][q * 4] = xpref;
      }
    }
    barrier_lds();
  }

  // ---- Tail: enc(h(0)) -> ctx[0] + s_ctx0; qz0 head; z0 + KL
  if (tid >= 384) {
    int e = tid - 384, ks = e >> 6, cc = e & 63;
#pragma unroll
    for (int b = 0; b < 2; ++b) {
      float a = 0.f;
      const uint4* hq = (const uint4*)&s_h[b][ks * 32];
#pragma unroll
      for (int j = 0; j < 8; ++j) {
        uint4 v = hq[j];
        DOT4(a, wA[4 * j], wA[4 * j + 1], wA[4 * j + 2], wA[4 * j + 3], v);
      }
      s_encp[(b * 64 + cc) * 2 + ks] = a;
    }
  }
  __syncthreads();
  if (tid >= 384) {
    int e = tid - 384, cc = e & 63, b = e >> 6;
    float2 p = *(const float2*)&s_encp[(b * 64 + cc) * 2];
    float val = p.x + p.y + encbr;
    ctx[((size_t)bbase + b) * 64 + cc] = (f16)val;
    s_ctx0[b][cc] = val;
  }
  __syncthreads();
  if (tid < 64) {
    int b = tid >> 5, o = tid & 31;
    float acc = qz0_b[o];
#pragma unroll 8
    for (int k = 0; k < 64; ++k) acc += qz0_w[o * 64 + k] * s_ctx0[b][k];
    s_q[b][o] = acc;
  }
  __syncthreads();
  if (tid < 32) {
    int b = tid >> 4, l = tid & 15;
    int bg = bbase + b;
    float qm = s_q[b][l], qls = s_q[b][16 + l];
    float z0v = qm + __expf(qls) * z0_noise[bg * 16 + l];
    z0_out[bg * 16 + l] = z0v;
    float pm = pz0_mean[l], pls = pz0_logstd[l];
    float var_q = __expf(2.0f * qls);
    float var_p = __expf(2.0f * pls);
    float dm = qm - pm;
    float kl = pls - qls + (var_q + dm * dm) / (2.0f * var_p) - 0.5f;
    atomicAdd(&accums[5], kl);
  }
}

// ---------------------------------------------------------------------------
// Kernel 3: SDE scan.  512 blocks x 256 threads, 1 batch/block, 2 blocks/CU.
// TWO barriers/step (R8 structure); L3 weights now REGISTER-resident per
// thread (was per-lane LDS reads — the only divergent LDS reads in the loop).
// ---------------------------------------------------------------------------
__global__ __launch_bounds__(256, 2) void k_sde(
    const f16* __restrict__ ctx, const float* __restrict__ z0_in,
    const float* __restrict__ ts, const float* __restrict__ bm_noise,
    const float* __restrict__ fw1, const float* __restrict__ fb1,
    const float* __restrict__ fw2, const float* __restrict__ fb2,
    const float* __restrict__ fw3, const float* __restrict__ fb3,
    const float* __restrict__ hw1, const float* __restrict__ hb1,
    const float* __restrict__ hw2, const float* __restrict__ hb2,
    const float* __restrict__ hw3, const float* __restrict__ hb3,
    const float* __restrict__ g_tab,
    f16* __restrict__ zs, float* __restrict__ accums) {
  __shared__ uint32_t s_x2[2][40];   // [p][ z(8 u32) | ctx(32 u32) ]
  __shared__ uint32_t s_h1[2][64];   // [mlp] layer-1 act
  __shared__ uint32_t s_h2[2][64];   // [mlp] layer-2 act
  __shared__ float s_dts[T_STEPS];

  const int tid = threadIdx.x;
  const int lane = tid & 63;
  const int bg = blockIdx.x;
  const uint4* ctx4 = (const uint4*)ctx;

  // role indices
  const int r1 = tid >> 1, hh = tid & 1;            // L1 half-rows
  const int mlp = tid >> 7, u2 = tid & 127;         // L2
  const int r3 = lane >> 1;                         // L3: 0..31
  const int net3 = r3 >> 4;                         // 0=f3, 1=h3
  const int l3 = r3 & 15;
  const int hh3 = lane & 1;
  const bool zlane = (net3 == 0) && (hh3 == 0);     // lane = 2*l3
  const bool stg = (tid >= 32 && tid < 40);         // ctx stagers (wave0)

  // ---- weight preload
  uint32_t uw1f[20], uw1h[4], wP2[64];
  uint4 w3r[8];
  float bf1r, bh1r, bias2r, fb3r, hb3r;
  {
    const float* w = fw1 + (size_t)r1 * 80 + hh * 40;
#pragma unroll
    for (int i = 0; i < 20; ++i) uw1f[i] = packh2(w[2 * i], w[2 * i + 1]);
    bf1r = fb1[r1];
  }
  {
    const float* w = hw1 + (size_t)r1 * 16 + hh * 8;
#pragma unroll
    for (int i = 0; i < 4; ++i) uw1h[i] = packh2(w[2 * i], w[2 * i + 1]);
    bh1r = hb1[r1];
  }
  {
    const float* w = (mlp ? hw2 : fw2) + (size_t)u2 * 128;
#pragma unroll
    for (int i = 0; i < 64; ++i) wP2[i] = packh2(w[2 * i], w[2 * i + 1]);
    bias2r = (mlp ? hb2 : fb2)[u2];
  }
  fb3r = fb3[l3];
  hb3r = hb3[l3];
  {
    const float* w = (net3 ? hw3 : fw3) + (size_t)l3 * 128 + hh3 * 64;
#pragma unroll
    for (int j = 0; j < 8; ++j) {
      uint4 q;
      q.x = packh2(w[8 * j + 0], w[8 * j + 1]);
      q.y = packh2(w[8 * j + 2], w[8 * j + 3]);
      q.z = packh2(w[8 * j + 4], w[8 * j + 5]);
      q.w = packh2(w[8 * j + 6], w[8 * j + 7]);
      w3r[j] = q;
    }
  }
  for (int i = tid; i < T_STEPS - 1; i += 256) s_dts[i] = ts[i + 1] - ts[i];

  // ---- state init
  float zreg = 0.f, bmc = 0.f, bmn = 0.f, gvp = 0.f, path_acc = 0.f;
  uint4 cpref = make_uint4(0, 0, 0, 0);
  if (zlane) {
    zreg = z0_in[bg * 16 + l3];
    ((f16*)&s_x2[0][0])[l3] = (f16)zreg;
    if (tid < 64) zs[(size_t)bg * 16 + l3] = (f16)zreg;
    bmc = bm_noise[(size_t)bg * 16 + l3];                       // bm[0]
    bmn = bm_noise[((size_t)1 * B_SZ + bg) * 16 + l3];          // bm[1]
    unsigned short zb = __builtin_bit_cast(unsigned short, (f16)zreg);
    gvp = g_tab[l3 * 65536 + (int)zb];
  }
  if (stg) {
    int q = tid - 32;
    uint4 v = ctx4[((size_t)1 * B_SZ + bg) * 8 + q];
    *(uint4*)&s_x2[0][8 + q * 4] = v;
  }
  __syncthreads();

  for (int t = 0; t < T_STEPS - 1; ++t) {
    const int p = t & 1;
    if (stg && t <= T_STEPS - 3)
      cpref = ctx4[((size_t)(t + 2) * B_SZ + bg) * 8 + (tid - 32)];
    // ---- Phase A part 1: L3(t-1) + z-update (redundant per wave)
    if (t > 0) {
      const uint4* hq = (const uint4*)&s_h2[net3][hh3 * 32];
      float a0 = 0.f, a1 = 0.f;
#pragma unroll
      for (int j = 0; j < 8; j += 2) {
        uint4 w0 = w3r[j], w1v = w3r[j + 1];
        uint4 v0 = hq[j], v1 = hq[j + 1];
        DOT4(a0, w0.x, w0.y, w0.z, w0.w, v0);
        DOT4(a1, w1v.x, w1v.y, w1v.z, w1v.w, v1);
      }
      float a = a0 + a1;
      float full = a + __shfl_xor(a, 1);    // combine 64-wide halves
      float cross = __shfl_xor(full, 32);   // f <-> h rows (same l3)
      if (zlane) {
        float fv = full + fb3r;
        float hv = cross + hb3r;
        float gv = gvp;
        float dt = s_dts[t - 1];
        float u_ = (fv - hv) / gv;
        float ls = u_ * u_;
        ls += __shfl_xor(ls, 2);
        ls += __shfl_xor(ls, 4);
        ls += __shfl_xor(ls, 8);
        ls += __shfl_xor(ls, 16);
        if (tid == 0) path_acc += 0.5f * ls * dt;
        float dw = sqrtf(dt) * bmc;
        float zn = zreg + fv * dt + gv * dw;
        zreg = zn;
        ((f16*)&s_x2[p][0])[l3] = (f16)zn;   // identical across waves
        if (tid < 64) zs[((size_t)t * B_SZ + bg) * 16 + l3] = (f16)zn;
        bmc = bmn;
        if (t <= T_STEPS - 3)
          bmn = bm_noise[((size_t)(t + 1) * B_SZ + bg) * 16 + l3];
        unsigned short zb = __builtin_bit_cast(unsigned short, (f16)zn);
        gvp = g_tab[l3 * 65536 + (int)zb];
      }
    }
    // ---- Phase A part 2: L1(t) half-rows
    {
      const uint4* xq = (const uint4*)&s_x2[p][0];
      const int base = hh * 5;
      float a0 = 0.f, a1 = 0.f;
      {
        uint4 v0 = xq[base + 0], v1 = xq[base + 1];
        DOT4(a0, uw1f[0], uw1f[1], uw1f[2], uw1f[3], v0);
        DOT4(a1, uw1f[4], uw1f[5], uw1f[6], uw1f[7], v1);
        uint4 v2 = xq[base + 2], v3 = xq[base + 3];
        DOT4(a0, uw1f[8], uw1f[9], uw1f[10], uw1f[11], v2);
        DOT4(a1, uw1f[12], uw1f[13], uw1f[14], uw1f[15], v3);
        uint4 v4 = xq[base + 4];
        DOT4(a0, uw1f[16], uw1f[17], uw1f[18], uw1f[19], v4);
      }
      float af = a0 + a1;
      uint4 vz = xq[hh];
      float ah = 0.f;
      DOT4(ah, uw1h[0], uw1h[1], uw1h[2], uw1h[3], vz);
      float ff = af + __shfl_xor(af, 1);
      float fh = ah + __shfl_xor(ah, 1);
      if (hh == 0)
        ((f16*)&s_h1[0][0])[r1] = (f16)softplusf_(ff + bf1r);
      else
        ((f16*)&s_h1[1][0])[r1] = (f16)softplusf_(fh + bh1r);
    }
    barrier_lds();
    // ---- Phase B: L2 full rows
    {
      const uint4* hq = (const uint4*)&s_h1[mlp][0];
      float a0 = 0.f, a1 = 0.f;
#pragma unroll
      for (int j = 0; j < 16; j += 2) {
        uint4 v0 = hq[j], v1 = hq[j + 1];
        DOT4(a0, wP2[4 * j], wP2[4 * j + 1], wP2[4 * j + 2], wP2[4 * j + 3], v0);
        DOT4(a1, wP2[4 * j + 4], wP2[4 * j + 5], wP2[4 * j + 6], wP2[4 * j + 7], v1);
      }
      ((f16*)&s_h2[mlp][0])[u2] = (f16)softplusf_(a0 + a1 + bias2r);
    }
    if (stg && t <= T_STEPS - 3)
      *(uint4*)&s_x2[p ^ 1][8 + (tid - 32) * 4] = cpref;
    barrier_lds();
  }

  // ---- Tail: L3(510) -> z(511) (wave0 only)
  if (tid < 64) {
    const uint4* hq = (const uint4*)&s_h2[net3][hh3 * 32];
    float a0 = 0.f, a1 = 0.f;
#pragma unroll
    for (int j = 0; j < 8; j += 2) {
      uint4 w0 = w3r[j], w1v = w3r[j + 1];
      uint4 v0 = hq[j], v1 = hq[j + 1];
      DOT4(a0, w0.x, w0.y, w0.z, w0.w, v0);
      DOT4(a1, w1v.x, w1v.y, w1v.z, w1v.w, v1);
    }
    float a = a0 + a1;
    float full = a + __shfl_xor(a, 1);
    float cross = __shfl_xor(full, 32);
    if (zlane) {
      float fv = full + fb3r;
      float hv = cross + hb3r;
      float gv = gvp;
      float dt = s_dts[T_STEPS - 2];
      float u_ = (fv - hv) / gv;
      float ls = u_ * u_;
      ls += __shfl_xor(ls, 2);
      ls += __shfl_xor(ls, 4);
      ls += __shfl_xor(ls, 8);
      ls += __shfl_xor(ls, 16);
      if (tid == 0) path_acc += 0.5f * ls * dt;
      float dw = sqrtf(dt) * bmc;
      float zn = zreg + fv * dt + gv * dw;
      zs[((size_t)(T_STEPS - 1) * B_SZ + bg) * 16 + l3] = (f16)zn;
    }
  }
  if (tid == 0) atomicAdd(&accums[6], path_acc);
}

// ---------------------------------------------------------------------------
// Kernel 4: decoder + losses.  One thread per (t,b).
// ---------------------------------------------------------------------------
__global__ __launch_bounds__(256) void k_dec(
    const f16* __restrict__ zs, const f16* __restrict__ state_t,
    const float* __restrict__ xs, const float* __restrict__ proj_w,
    const float* __restrict__ proj_b, const float* __restrict__ act_w,
    const float* __restrict__ act_b, const float* __restrict__ land_w,
    const float* __restrict__ shot_w, const float* __restrict__ move_w,
    float* __restrict__ accums) {
  __shared__ uint32_t s_proj[8 * 32];
  __shared__ uint32_t s_act[8 * 128];
  __shared__ uint32_t s_head[128 * 8];
  __shared__ float s_pb[32], s_ab[128];
  __shared__ float s_red[4 * 5];

  const int tid = threadIdx.x;
  for (int id = tid; id < 8 * 32; id += 256) {
    int kp = id & 7, n = id >> 3;
    s_proj[kp * 32 + n] = packh2(proj_w[n * 16 + 2 * kp], proj_w[n * 16 + 2 * kp + 1]);
  }
  for (int id = tid; id < 8 * 128; id += 256) {
    int kp = id & 7, n = id >> 3;
    s_act[kp * 128 + n] = packh2(act_w[n * 16 + 2 * kp], act_w[n * 16 + 2 * kp + 1]);
  }
  for (int id = tid; id < 128 * 8; id += 256) {
    int j = id >> 3, p = id & 7;
    int h0 = 2 * p, h1 = 2 * p + 1;
    float w0 = (h0 < 2) ? land_w[h0 * 128 + j]
                        : (h0 < 14 ? shot_w[(h0 - 2) * 128 + j]
                                   : move_w[(h0 - 14) * 128 + j]);
    float w1 = (h1 < 2) ? land_w[h1 * 128 + j]
                        : (h1 < 14 ? shot_w[(h1 - 2) * 128 + j]
                                   : move_w[(h1 - 14) * 128 + j]);
    s_head[j * 8 + p] = packh2(w0, w1);
  }
  if (tid < 32) s_pb[tid] = proj_b[tid];
  if (tid < 128) s_ab[tid] = act_b[tid];
  __syncthreads();

  size_t idx = (size_t)blockIdx.x * 256 + tid;
  uint32_t z2[8];
  const uint32_t* zp = (const uint32_t*)(zs + idx * 16);
#pragma unroll
  for (int i = 0; i < 8; ++i) z2[i] = zp[i];
  uint32_t stv[16];
  const uint32_t* stp = (const uint32_t*)(state_t + idx * 32);
#pragma unroll
  for (int i = 0; i < 16; ++i) stv[i] = stp[i];

  float sqsum = 0.0f;
#pragma unroll 4
  for (int i = 0; i < 32; ++i) {
    float acc = s_pb[i];
#pragma unroll
    for (int kp = 0; kp < 8; ++kp) acc = fdot2(s_proj[kp * 32 + i], z2[kp], acc);
    f16x2 sv = __builtin_bit_cast(f16x2, stv[i >> 1]);
    float d = (float)sv[i & 1] - acc;
    sqsum += d * d;
  }

  float hd[16];
#pragma unroll
  for (int i = 0; i < 16; ++i) hd[i] = 0.0f;
#pragma unroll 2
  for (int j = 0; j < 128; ++j) {
    float a = s_ab[j];
#pragma unroll
    for (int kp = 0; kp < 8; ++kp) a = fdot2(s_act[kp * 128 + j], z2[kp], a);
    a = fmaxf(a, 0.0f);
#pragma unroll
    for (int p = 0; p < 8; ++p) {
      f16x2 w = __builtin_bit_cast(f16x2, s_head[j * 8 + p]);
      hd[2 * p] += (float)w[0] * a;
      hd[2 * p + 1] += (float)w[1] * a;
    }
  }
  const float* xp = xs + idx * 23;
  float dl0 = hd[0] - xp[18], dl1 = hd[1] - xp[19];
  float land = dl0 * dl0 + dl1 * dl1;
  float dm0 = hd[14] - xp[21], dm1 = hd[15] - xp[22];
  float move = dm0 * dm0 + dm1 * dm1;
  int sid = (int)xp[20];
  float m = hd[2];
#pragma unroll
  for (int s = 1; s < 12; ++s) m = fmaxf(m, hd[2 + s]);
  float sume = 0.0f;
#pragma unroll
  for (int s = 0; s < 12; ++s) sume += __expf(hd[2 + s] - m);
  float lse = m + __logf(sume);
  float pl = 0.0f;
#pragma unroll
  for (int s = 0; s < 12; ++s)
    if (s == sid) pl = hd[2 + s];
  float picked = 0.0f, cnt = 0.0f;
  if (sid != 0) {
    picked = pl - lse;
    cnt = 1.0f;
  }
  float vals[5] = {sqsum, land, move, picked, cnt};
#pragma unroll
  for (int v = 0; v < 5; ++v) {
    float x = vals[v];
    for (int off = 1; off < 64; off <<= 1) x += __shfl_xor(x, off);
    vals[v] = x;
  }
  int lane = tid & 63, wv = tid >> 6;
  if (lane == 0) {
#pragma unroll
    for (int v = 0; v < 5; ++v) s_red[wv * 5 + v] = vals[v];
  }
  __syncthreads();
  if (tid == 0) {
#pragma unroll
    for (int v = 0; v < 5; ++v) {
      float s = s_red[v] + s_red[5 + v] + s_red[10 + v] + s_red[15 + v];
      atomicAdd(&accums[v], s);
    }
  }
}

// ---------------------------------------------------------------------------
// Kernel 5: finalize the two scalar outputs.
// ---------------------------------------------------------------------------
__global__ void k_fin(const float* __restrict__ accums,
                      const float* __restrict__ noise_std,
                      float* __restrict__ out) {
  if (threadIdx.x == 0 && blockIdx.x == 0) {
    float sd = noise_std[0];
    float log_pxs = -0.5f * accums[0] / (sd * sd * (float)B_SZ) -
                    (float)T_STEPS * 32.0f * (logf(sd) + 0.5f * LOG2PI);
    float land = accums[1] / (float)(T_STEPS * B_SZ * 2);
    float move = accums[2] / (float)(T_STEPS * B_SZ * 2);
    float shot = -accums[3] / fmaxf(accums[4], 1.0f);
    float out1 = accums[5] / (float)B_SZ + accums[6] / (float)B_SZ + land + shot + move;
    out[0] = log_pxs;
    out[1] = out1;
  }
}

// ---------------------------------------------------------------------------
extern "C" void kernel_launch(void* const* d_in, const int* in_sizes, int n_in,
                              void* d_out, int out_size, void* d_ws,
                              size_t ws_size, hipStream_t stream) {
  const float* xs = (const float*)d_in[1];
  const float* ts = (const float*)d_in[2];
  const float* noise_std = (const float*)d_in[3];
  const float* z0_noise = (const float*)d_in[4];
  const float* bm_noise = (const float*)d_in[5];
  const float* shot_emb = (const float*)d_in[6];
  const float* player_emb = (const float*)d_in[7];
  const float* gru_wih = (const float*)d_in[8];
  const float* gru_whh = (const float*)d_in[9];
  const float* gru_bih = (const float*)d_in[10];
  const float* gru_bhh = (const float*)d_in[11];
  const float* enc_w = (const float*)d_in[12];
  const float* enc_b = (const float*)d_in[13];
  const float* qz0_w = (const float*)d_in[14];
  const float* qz0_b = (const float*)d_in[15];
  const float* f_w1 = (const float*)d_in[16];
  const float* f_b1 = (const float*)d_in[17];
  const float* f_w2 = (const float*)d_in[18];
  const float* f_b2 = (const float*)d_in[19];
  const float* f_w3 = (const float*)d_in[20];
  const float* f_b3 = (const float*)d_in[21];
  const float* h_w1 = (const float*)d_in[22];
  const float* h_b1 = (const float*)d_in[23];
  const float* h_w2 = (const float*)d_in[24];
  const float* h_b2 = (const float*)d_in[25];
  const float* h_w3 = (const float*)d_in[26];
  const float* h_b3 = (const float*)d_in[27];
  const float* g_w1 = (const float*)d_in[28];
  const float* g_b1 = (const float*)d_in[29];
  const float* g_w2 = (const float*)d_in[30];
  const float* g_b2 = (const float*)d_in[31];
  const float* proj_w = (const float*)d_in[32];
  const float* proj_b = (const float*)d_in[33];
  const float* pz0_mean = (const float*)d_in[34];
  const float* pz0_logstd = (const float*)d_in[35];
  const float* act_w = (const float*)d_in[36];
  const float* act_b = (const float*)d_in[37];
  const float* act_land_w = (const float*)d_in[38];
  const float* act_shot_w = (const float*)d_in[39];
  const float* act_move_w = (const float*)d_in[40];

  char* ws = (char*)d_ws;
  float* accums = (float*)ws;                       // 16 floats (256 B reserved)
  f16* state_t = (f16*)(ws + 256);                  // T*B*32 f16 = 16 MB
  f16* ctx = (f16*)(ws + 256 + 16777216);           // T*B*64 f16 = 32 MB
  float* z0b = (float*)(ws + 256 + 16777216 + 33554432);   // B*16 f32
  f16* zs = (f16*)(ws + 256 + 16777216 + 33554432 + 32768);  // T*B*16 f16 = 8 MB
  float* g_tab = (float*)(ws + 256 + 16777216 + 33554432 + 32768 + 8388608);  // 4 MB

  k_embed<<<1024, 256, 0, stream>>>(xs, shot_emb, player_emb, state_t, accums);
  k_gtab<<<4096, 256, 0, stream>>>(g_w1, g_b1, g_w2, g_b2, g_tab);
  k_gru<<<256, 512, 0, stream>>>(state_t, gru_wih, gru_whh, gru_bih, gru_bhh,
                                 enc_w, enc_b, qz0_w, qz0_b, z0_noise, pz0_mean,
                                 pz0_logstd, ctx, z0b, accums);
  k_sde<<<512, 256, 0, stream>>>(ctx, z0b, ts, bm_noise, f_w1, f_b1, f_w2, f_b2,
                                 f_w3, f_b3, h_w1, h_b1, h_w2, h_b2, h_w3, h_b3,
                                 g_tab, zs, accums);
  k_dec<<<1024, 256, 0, stream>>>(zs, state_t, xs, proj_w, proj_b, act_w, act_b,
                                  act_land_w, act_shot_w, act_move_w, accums);
  k_fin<<<1, 64, 0, stream>>>(accums, noise_std, (float*)d_out);
}

// Round 10
// 1632.401 us; speedup vs baseline: 1.3464x; 1.0642x over previous
//
#include <hip/hip_runtime.h>
#include <cstdint>

typedef _Float16 f16;
typedef _Float16 f16x2 __attribute__((ext_vector_type(2)));

#define T_STEPS 512
#define B_SZ 512
#define LOG2PI 1.8378770664093453f

// Raw barrier: drain LDS only (NOT vmcnt) so in-flight global prefetch loads
// and stores survive across the barrier.
__device__ __forceinline__ void barrier_lds() {
  asm volatile("s_waitcnt lgkmcnt(0)" ::: "memory");
  __builtin_amdgcn_s_barrier();
  asm volatile("" ::: "memory");
}

__device__ __forceinline__ uint32_t packh2(float a, float b) {
  f16x2 v; v[0] = (f16)a; v[1] = (f16)b;
  return __builtin_bit_cast(uint32_t, v);
}

__device__ __forceinline__ float fdot2(uint32_t a, uint32_t b, float c) {
#if defined(__AMDGCN__) && __has_builtin(__builtin_amdgcn_fdot2)
  return __builtin_amdgcn_fdot2(__builtin_bit_cast(f16x2, a),
                                __builtin_bit_cast(f16x2, b), c, false);
#else
  f16x2 x = __builtin_bit_cast(f16x2, a), y = __builtin_bit_cast(f16x2, b);
  return c + (float)x[0] * (float)y[0] + (float)x[1] * (float)y[1];
#endif
}

#define DOT4(acc, w0, w1, w2, w3, v)                                     \
  do {                                                                   \
    acc = fdot2((w0), (v).x, acc); acc = fdot2((w1), (v).y, acc);        \
    acc = fdot2((w2), (v).z, acc); acc = fdot2((w3), (v).w, acc);        \
  } while (0)

__device__ __forceinline__ float sigmoidf_(float x) {
  return 1.0f / (1.0f + __expf(-x));
}
__device__ __forceinline__ float tanhf_(float x) {
  float ax = fabsf(x);
  float t = __expf(-2.0f * ax);
  float r = (1.0f - t) / (1.0f + t);
  return copysignf(r, x);
}
__device__ __forceinline__ float softplusf_(float x) {
  return fmaxf(x, 0.0f) + __logf(1.0f + __expf(-fabsf(x)));
}

// ---------------------------------------------------------------------------
// Kernel 1: embedding / state_t construction.  state_t: (T,B,32) f16.
// ---------------------------------------------------------------------------
__global__ __launch_bounds__(256) void k_embed(
    const float* __restrict__ xs, const float* __restrict__ shot_emb,
    const float* __restrict__ player_emb, f16* __restrict__ state_t,
    float* __restrict__ accums) {
  if (blockIdx.x == 0 && threadIdx.x < 16) accums[threadIdx.x] = 0.0f;
  size_t idx = (size_t)blockIdx.x * 256 + threadIdx.x;
  const float* xp = xs + idx * 23;
  f16* op = state_t + idx * 32;
  int sid = (int)xp[12];
  int pid = (int)xp[17];
#pragma unroll
  for (int i = 0; i < 12; ++i) op[i] = (f16)xp[i];
  const float* se = shot_emb + sid * 8;
#pragma unroll
  for (int i = 0; i < 8; ++i) op[12 + i] = (f16)se[i];
#pragma unroll
  for (int i = 0; i < 4; ++i) op[20 + i] = (f16)xp[13 + i];
  const float* pe = player_emb + pid * 8;
#pragma unroll
  for (int i = 0; i < 8; ++i) op[24 + i] = (f16)pe[i];
}

// ---------------------------------------------------------------------------
// Kernel 1b: g-network lookup table (R6-verified).  16 x 65536 f32 = 4 MB.
// ---------------------------------------------------------------------------
__global__ __launch_bounds__(256) void k_gtab(
    const float* __restrict__ gw1, const float* __restrict__ gb1,
    const float* __restrict__ gw2, const float* __restrict__ gb2,
    float* __restrict__ g_tab) {
  int gid = blockIdx.x * 256 + threadIdx.x;
  int l = gid >> 16, yi = gid & 0xffff;
  f16 hy = __builtin_bit_cast(f16, (unsigned short)yi);
  float y = (float)hy;
  const float* w1 = gw1 + l * 128;
  const float* b1 = gb1 + l * 128;
  const float* w2 = gw2 + l * 128;
  float a0 = 0.f, a1 = 0.f;
#pragma unroll 8
  for (int h = 0; h < 128; h += 2) {
    a0 = fmaf(softplusf_(fmaf(y, w1[h], b1[h])), w2[h], a0);
    a1 = fmaf(softplusf_(fmaf(y, w1[h + 1], b1[h + 1])), w2[h + 1], a1);
  }
  g_tab[gid] = sigmoidf_(a0 + a1 + gb2[l]);
}

// ---------------------------------------------------------------------------
// Kernel 2: backward GRU scan + encoder + qz0 head.  (best-known version)
// 256 blocks x 512 threads, 2 batch/block.  2 LDS-only barriers/step.
// ---------------------------------------------------------------------------
__global__ __launch_bounds__(512) void k_gru(
    const f16* __restrict__ state_t, const float* __restrict__ wih,
    const float* __restrict__ whh, const float* __restrict__ bih,
    const float* __restrict__ bhh, const float* __restrict__ enc_w,
    const float* __restrict__ enc_b, const float* __restrict__ qz0_w,
    const float* __restrict__ qz0_b, const float* __restrict__ z0_noise,
    const float* __restrict__ pz0_mean, const float* __restrict__ pz0_logstd,
    f16* __restrict__ ctx, float* __restrict__ z0_out,
    float* __restrict__ accums) {
  __shared__ uint32_t s_x[2][16];      // x_t, f16x2 packed
  __shared__ uint32_t s_h[2][64];      // h,   f16x2 packed
  __shared__ float s_gates[2 * 128 * 4];  // [b][du][R,Z,iN,hN]
  __shared__ float s_encp[2 * 64 * 2];    // [b][c][ks]
  __shared__ float s_ctx0[2][64];
  __shared__ float s_q[2][32];

  const int tid = threadIdx.x;
  const int bbase = blockIdx.x * 2;
  const uint32_t* stu = (const uint32_t*)state_t;

  uint32_t wA[64];   // whh row (RZ/N) | enc half-row (enc, 32 used)
  uint32_t wB[16];   // wih row (RZ/N)
  float bias0 = 0.f, bias1 = 0.f, encbr = 0.f;

  if (tid < 256) {
    int g = tid >> 7, du = tid & 127;
    const float* whr = whh + (size_t)(g * 128 + du) * 128;
#pragma unroll
    for (int i = 0; i < 64; ++i) wA[i] = packh2(whr[2 * i], whr[2 * i + 1]);
    const float* wxr = wih + (size_t)(g * 128 + du) * 32;
#pragma unroll
    for (int i = 0; i < 16; ++i) wB[i] = packh2(wxr[2 * i], wxr[2 * i + 1]);
    bias0 = bih[g * 128 + du] + bhh[g * 128 + du];
  } else if (tid < 384) {
    int du = tid - 256;
    const float* whr = whh + (size_t)(256 + du) * 128;
#pragma unroll
    for (int i = 0; i < 64; ++i) wA[i] = packh2(whr[2 * i], whr[2 * i + 1]);
    const float* wxr = wih + (size_t)(256 + du) * 32;
#pragma unroll
    for (int i = 0; i < 16; ++i) wB[i] = packh2(wxr[2 * i], wxr[2 * i + 1]);
    bias0 = bih[256 + du];
    bias1 = bhh[256 + du];
  } else {
    int e = tid - 384, c = e & 63, ks = e >> 6;
    const float* wer = enc_w + (size_t)c * 128 + ks * 64;
#pragma unroll
    for (int i = 0; i < 32; ++i) wA[i] = packh2(wer[2 * i], wer[2 * i + 1]);
    encbr = enc_b[c];
  }

  if (tid < 128) s_h[tid >> 6][tid & 63] = 0u;
  if (tid < 32) {
    int b = tid >> 4, i = tid & 15;
    s_x[b][i] = stu[((size_t)(T_STEPS - 1) * B_SZ + bbase + b) * 16 + i];
  }
  float h_old = 0.0f;
  __syncthreads();

  for (int t = T_STEPS - 1; t >= 0; --t) {
    uint4 xpref = make_uint4(0, 0, 0, 0);
    // ---- Phase A: gate dots (R/Z/N) + enc dots for h(t+1) + x prefetch
    if (tid < 256) {
      int g = tid >> 7, du = tid & 127;
#pragma unroll
      for (int b = 0; b < 2; ++b) {
        float a = bias0;
        const uint4* xq = (const uint4*)&s_x[b][0];
#pragma unroll
        for (int j = 0; j < 4; ++j) {
          uint4 v = xq[j];
          DOT4(a, wB[4 * j], wB[4 * j + 1], wB[4 * j + 2], wB[4 * j + 3], v);
        }
        const uint4* hq = (const uint4*)&s_h[b][0];
#pragma unroll
        for (int j = 0; j < 16; ++j) {
          uint4 v = hq[j];
          DOT4(a, wA[4 * j], wA[4 * j + 1], wA[4 * j + 2], wA[4 * j + 3], v);
        }
        s_gates[(b * 128 + du) * 4 + g] = a;
      }
    } else if (tid < 384) {
      int du = tid - 256;
#pragma unroll
      for (int b = 0; b < 2; ++b) {
        float aI = bias0, aH = bias1;
        const uint4* xq = (const uint4*)&s_x[b][0];
#pragma unroll
        for (int j = 0; j < 4; ++j) {
          uint4 v = xq[j];
          DOT4(aI, wB[4 * j], wB[4 * j + 1], wB[4 * j + 2], wB[4 * j + 3], v);
        }
        const uint4* hq = (const uint4*)&s_h[b][0];
#pragma unroll
        for (int j = 0; j < 16; ++j) {
          uint4 v = hq[j];
          DOT4(aH, wA[4 * j], wA[4 * j + 1], wA[4 * j + 2], wA[4 * j + 3], v);
        }
        s_gates[(b * 128 + du) * 4 + 2] = aI;
        s_gates[(b * 128 + du) * 4 + 3] = aH;
      }
    } else {
      int e = tid - 384, ks = e >> 6, cc = e & 63;
      (void)cc;
      if (t < T_STEPS - 1) {
#pragma unroll
        for (int b = 0; b < 2; ++b) {
          float a = 0.f;
          const uint4* hq = (const uint4*)&s_h[b][ks * 32];
#pragma unroll
          for (int j = 0; j < 8; ++j) {
            uint4 v = hq[j];
            DOT4(a, wA[4 * j], wA[4 * j + 1], wA[4 * j + 2], wA[4 * j + 3], v);
          }
          s_encp[(b * 64 + cc) * 2 + ks] = a;
        }
      }
      if (e < 8 && t > 0) {
        int b = e & 1, q = e >> 1;
        xpref = *(const uint4*)(stu +
                                ((size_t)(t - 1) * B_SZ + bbase + b) * 16 + q * 4);
      }
    }
    barrier_lds();
    // ---- Phase B: h update; ctx combine; x stage
    if (tid < 256) {
      int b = tid >> 7, du = tid & 127;
      const float4 gt = *(const float4*)&s_gates[(b * 128 + du) * 4];
      float r = sigmoidf_(gt.x), zg = sigmoidf_(gt.y);
      float n = tanhf_(gt.z + r * gt.w);
      float hnew = (1.0f - zg) * n + zg * h_old;
      h_old = hnew;
      ((f16*)&s_h[b][0])[du] = (f16)hnew;
    } else if (tid >= 384) {
      int e = tid - 384, cc = e & 63, b = e >> 6;
      if (t < T_STEPS - 1) {
        float2 p = *(const float2*)&s_encp[(b * 64 + cc) * 2];
        ctx[((size_t)(t + 1) * B_SZ + bbase + b) * 64 + cc] =
            (f16)(p.x + p.y + encbr);
      }
      if (e < 8 && t > 0) {
        int b2 = e & 1, q = e >> 1;
        *(uint4*)&s_x[b2][q * 4] = xpref;
      }
    }
    barrier_lds();
  }

  // ---- Tail: enc(h(0)) -> ctx[0] + s_ctx0; qz0 head; z0 + KL
  if (tid >= 384) {
    int e = tid - 384, ks = e >> 6, cc = e & 63;
#pragma unroll
    for (int b = 0; b < 2; ++b) {
      float a = 0.f;
      const uint4* hq = (const uint4*)&s_h[b][ks * 32];
#pragma unroll
      for (int j = 0; j < 8; ++j) {
        uint4 v = hq[j];
        DOT4(a, wA[4 * j], wA[4 * j + 1], wA[4 * j + 2], wA[4 * j + 3], v);
      }
      s_encp[(b * 64 + cc) * 2 + ks] = a;
    }
  }
  __syncthreads();
  if (tid >= 384) {
    int e = tid - 384, cc = e & 63, b = e >> 6;
    float2 p = *(const float2*)&s_encp[(b * 64 + cc) * 2];
    float val = p.x + p.y + encbr;
    ctx[((size_t)bbase + b) * 64 + cc] = (f16)val;
    s_ctx0[b][cc] = val;
  }
  __syncthreads();
  if (tid < 64) {
    int b = tid >> 5, o = tid & 31;
    float acc = qz0_b[o];
#pragma unroll 8
    for (int k = 0; k < 64; ++k) acc += qz0_w[o * 64 + k] * s_ctx0[b][k];
    s_q[b][o] = acc;
  }
  __syncthreads();
  if (tid < 32) {
    int b = tid >> 4, l = tid & 15;
    int bg = bbase + b;
    float qm = s_q[b][l], qls = s_q[b][16 + l];
    float z0v = qm + __expf(qls) * z0_noise[bg * 16 + l];
    z0_out[bg * 16 + l] = z0v;
    float pm = pz0_mean[l], pls = pz0_logstd[l];
    float var_q = __expf(2.0f * qls);
    float var_p = __expf(2.0f * pls);
    float dm = qm - pm;
    float kl = pls - qls + (var_q + dm * dm) / (2.0f * var_p) - 0.5f;
    atomicAdd(&accums[5], kl);
  }
}

// ---------------------------------------------------------------------------
// Kernel 3: SDE scan.  512 blocks x 256 threads, 1 batch/block, 2 blocks/CU.
// R6 3-phase structure (best-known, 832 us) + two issue-balance fixes:
//  P1: L1 as shfl-paired half-rows across all 256 threads (was 40 fdot2 on
//      the f1 waves, 8 on h1 waves -> now 24 balanced).
//  P3: L3 spread over 2 waves as quarter-rows (l=tid>>3, mlp=(tid>>2)&1,
//      kq=tid&3; 16 fdot2 each; shfl_xor 1,2 combine; shfl_xor 4 f<->h);
//      z-update on (tid&7)==0 lanes; path partials per wave.
// g-table / bm / ctx prefetches issued one phase ahead (latency hidden).
// ---------------------------------------------------------------------------
__global__ __launch_bounds__(256, 2) void k_sde(
    const f16* __restrict__ ctx, const float* __restrict__ z0_in,
    const float* __restrict__ ts, const float* __restrict__ bm_noise,
    const float* __restrict__ fw1, const float* __restrict__ fb1,
    const float* __restrict__ fw2, const float* __restrict__ fb2,
    const float* __restrict__ fw3, const float* __restrict__ fb3,
    const float* __restrict__ hw1, const float* __restrict__ hb1,
    const float* __restrict__ hw2, const float* __restrict__ hb2,
    const float* __restrict__ hw3, const float* __restrict__ hb3,
    const float* __restrict__ g_tab,
    f16* __restrict__ zs, float* __restrict__ accums) {
  __shared__ uint32_t s_x2[40];       // [z(8 u32) | ctx(32 u32)] f16x2
  __shared__ uint32_t s_h1[2][64];    // [mlp] layer-1 act, f16x2
  __shared__ uint32_t s_h2[2][64];    // [mlp] layer-2 act, f16x2
  __shared__ float s_dts[T_STEPS];

  const int tid = threadIdx.x;
  const int bg = blockIdx.x;
  const uint4* ctx4 = (const uint4*)ctx;

  // L1 roles (all 256): row r1 = tid>>1, half hh = tid&1
  const int r1 = tid >> 1, hh = tid & 1;
  // L2 roles (all 256)
  const int mlp2 = tid >> 7, u2 = tid & 127;
  // L3 roles (tid<128): l3 = tid>>3, mlp3 = (tid>>2)&1, quarter kq = tid&3
  const int l3 = (tid >> 3) & 15;
  const int mlp3 = (tid >> 2) & 1;
  const int kq = tid & 3;
  const bool p3act = (tid < 128);
  const bool zlane = p3act && ((tid & 7) == 0);
  const bool stg = (tid >= 128 && tid < 136);   // ctx stagers (wave 2)

  // ---- weight preload
  uint32_t uw1f[20], uw1h[4], wP2[64], wP3[16];
  float bf1r, bh1r, bias2r, fb3r = 0.f, hb3r = 0.f;
  {
    const float* w = fw1 + (size_t)r1 * 80 + hh * 40;
#pragma unroll
    for (int i = 0; i < 20; ++i) uw1f[i] = packh2(w[2 * i], w[2 * i + 1]);
    bf1r = fb1[r1];
  }
  {
    const float* w = hw1 + (size_t)r1 * 16 + hh * 8;
#pragma unroll
    for (int i = 0; i < 4; ++i) uw1h[i] = packh2(w[2 * i], w[2 * i + 1]);
    bh1r = hb1[r1];
  }
  {
    const float* w = (mlp2 ? hw2 : fw2) + (size_t)u2 * 128;
#pragma unroll
    for (int i = 0; i < 64; ++i) wP2[i] = packh2(w[2 * i], w[2 * i + 1]);
    bias2r = (mlp2 ? hb2 : fb2)[u2];
  }
  if (p3act) {
    const float* w = (mlp3 ? hw3 : fw3) + (size_t)l3 * 128 + kq * 32;
#pragma unroll
    for (int i = 0; i < 16; ++i) wP3[i] = packh2(w[2 * i], w[2 * i + 1]);
    fb3r = fb3[l3];
    hb3r = hb3[l3];
  }
  for (int i = tid; i < T_STEPS - 1; i += 256) s_dts[i] = ts[i + 1] - ts[i];

  // ---- state init
  float zreg = 0.f, bmc = 0.f, path_acc = 0.f;
  uint4 cpref = make_uint4(0, 0, 0, 0);
  if (zlane) {
    zreg = z0_in[bg * 16 + l3];
    ((f16*)&s_x2[0])[l3] = (f16)zreg;
    zs[(size_t)bg * 16 + l3] = (f16)zreg;
    bmc = bm_noise[(size_t)bg * 16 + l3];
  }
  if (stg) {
    int q = tid - 128;
    uint4 v = ctx4[((size_t)1 * B_SZ + bg) * 8 + q];
    *(uint4*)&s_x2[8 + q * 4] = v;
  }
  __syncthreads();

  for (int t = 0; t < T_STEPS - 1; ++t) {
    float bmn = 0.f, gvp = 0.f;
    // ---- issue g-table load (consumed in P3) + prefetch bm(t+1), ctx(t+2)
    if (zlane) {
      unsigned short zb = __builtin_bit_cast(unsigned short, (f16)zreg);
      gvp = g_tab[l3 * 65536 + (int)zb];
      if (t < T_STEPS - 2)
        bmn = bm_noise[((size_t)(t + 1) * B_SZ + bg) * 16 + l3];
    }
    if (stg && t <= T_STEPS - 3)
      cpref = ctx4[((size_t)(t + 2) * B_SZ + bg) * 8 + (tid - 128)];

    // ---- P1: L1 balanced half-rows (all 256 threads)
    {
      const uint4* xq = (const uint4*)&s_x2[0];
      const int base = hh * 5;
      float a0 = 0.f, a1 = 0.f;
      {
        uint4 v0 = xq[base + 0], v1 = xq[base + 1];
        DOT4(a0, uw1f[0], uw1f[1], uw1f[2], uw1f[3], v0);
        DOT4(a1, uw1f[4], uw1f[5], uw1f[6], uw1f[7], v1);
        uint4 v2 = xq[base + 2], v3 = xq[base + 3];
        DOT4(a0, uw1f[8], uw1f[9], uw1f[10], uw1f[11], v2);
        DOT4(a1, uw1f[12], uw1f[13], uw1f[14], uw1f[15], v3);
        uint4 v4 = xq[base + 4];
        DOT4(a0, uw1f[16], uw1f[17], uw1f[18], uw1f[19], v4);
      }
      float af = a0 + a1;
      uint4 vz = xq[hh];
      float ah = 0.f;
      DOT4(ah, uw1h[0], uw1h[1], uw1h[2], uw1h[3], vz);
      float ff = af + __shfl_xor(af, 1);
      float fh = ah + __shfl_xor(ah, 1);
      if (hh == 0)
        ((f16*)&s_h1[0][0])[r1] = (f16)softplusf_(ff + bf1r);
      else
        ((f16*)&s_h1[1][0])[r1] = (f16)softplusf_(fh + bh1r);
    }
    barrier_lds();
    // ---- P2: L2 full rows (all 256 threads)
    {
      const uint4* hq = (const uint4*)&s_h1[mlp2][0];
      float a0 = 0.f, a1 = 0.f;
#pragma unroll
      for (int j = 0; j < 16; j += 2) {
        uint4 v0 = hq[j], v1 = hq[j + 1];
        DOT4(a0, wP2[4 * j], wP2[4 * j + 1], wP2[4 * j + 2], wP2[4 * j + 3], v0);
        DOT4(a1, wP2[4 * j + 4], wP2[4 * j + 5], wP2[4 * j + 6], wP2[4 * j + 7], v1);
      }
      ((f16*)&s_h2[mlp2][0])[u2] = (f16)softplusf_(a0 + a1 + bias2r);
    }
    barrier_lds();
    // ---- P3: L3 quarter-rows over 2 waves + z update; ctx stage
    if (p3act) {
      const uint4* hq = (const uint4*)&s_h2[mlp3][kq * 16];
      float a0 = 0.f, a1 = 0.f;
#pragma unroll
      for (int j = 0; j < 4; j += 2) {
        uint4 v0 = hq[j], v1 = hq[j + 1];
        DOT4(a0, wP3[4 * j], wP3[4 * j + 1], wP3[4 * j + 2], wP3[4 * j + 3], v0);
        DOT4(a1, wP3[4 * j + 4], wP3[4 * j + 5], wP3[4 * j + 6], wP3[4 * j + 7], v1);
      }
      float a = a0 + a1;
      float s1 = a + __shfl_xor(a, 1);     // combine quarter pairs
      float s2 = s1 + __shfl_xor(s1, 2);   // full 128-wide row sum
      float other = __shfl_xor(s2, 4);     // exchange f <-> h (same l3)
      if ((tid & 7) == 0) {
        float fv = s2 + fb3r;
        float hv = other + hb3r;
        float gv = gvp;                    // table value, loaded at loop top
        float dt = s_dts[t];
        float u_ = (fv - hv) / gv;
        float ls = u_ * u_;
        ls += __shfl_xor(ls, 8);
        ls += __shfl_xor(ls, 16);
        ls += __shfl_xor(ls, 32);
        if ((tid & 63) == 0) path_acc += 0.5f * ls * dt;
        float dw = sqrtf(dt) * bmc;
        float zn = zreg + fv * dt + gv * dw;
        zreg = zn;
        ((f16*)&s_x2[0])[l3] = (f16)zn;
        zs[((size_t)(t + 1) * B_SZ + bg) * 16 + l3] = (f16)zn;
        bmc = bmn;
      }
    } else if (stg && t <= T_STEPS - 3) {
      *(uint4*)&s_x2[8 + (tid - 128) * 4] = cpref;
    }
    barrier_lds();
  }
  if (tid == 0 || tid == 64) atomicAdd(&accums[6], path_acc);
}

// ---------------------------------------------------------------------------
// Kernel 4: decoder + losses.  One thread per (t,b).
// ---------------------------------------------------------------------------
__global__ __launch_bounds__(256) void k_dec(
    const f16* __restrict__ zs, const f16* __restrict__ state_t,
    const float* __restrict__ xs, const float* __restrict__ proj_w,
    const float* __restrict__ proj_b, const float* __restrict__ act_w,
    const float* __restrict__ act_b, const float* __restrict__ land_w,
    const float* __restrict__ shot_w, const float* __restrict__ move_w,
    float* __restrict__ accums) {
  __shared__ uint32_t s_proj[8 * 32];
  __shared__ uint32_t s_act[8 * 128];
  __shared__ uint32_t s_head[128 * 8];
  __shared__ float s_pb[32], s_ab[128];
  __shared__ float s_red[4 * 5];

  const int tid = threadIdx.x;
  for (int id = tid; id < 8 * 32; id += 256) {
    int kp = id & 7, n = id >> 3;
    s_proj[kp * 32 + n] = packh2(proj_w[n * 16 + 2 * kp], proj_w[n * 16 + 2 * kp + 1]);
  }
  for (int id = tid; id < 8 * 128; id += 256) {
    int kp = id & 7, n = id >> 3;
    s_act[kp * 128 + n] = packh2(act_w[n * 16 + 2 * kp], act_w[n * 16 + 2 * kp + 1]);
  }
  for (int id = tid; id < 128 * 8; id += 256) {
    int j = id >> 3, p = id & 7;
    int h0 = 2 * p, h1 = 2 * p + 1;
    float w0 = (h0 < 2) ? land_w[h0 * 128 + j]
                        : (h0 < 14 ? shot_w[(h0 - 2) * 128 + j]
                                   : move_w[(h0 - 14) * 128 + j]);
    float w1 = (h1 < 2) ? land_w[h1 * 128 + j]
                        : (h1 < 14 ? shot_w[(h1 - 2) * 128 + j]
                                   : move_w[(h1 - 14) * 128 + j]);
    s_head[j * 8 + p] = packh2(w0, w1);
  }
  if (tid < 32) s_pb[tid] = proj_b[tid];
  if (tid < 128) s_ab[tid] = act_b[tid];
  __syncthreads();

  size_t idx = (size_t)blockIdx.x * 256 + tid;
  uint32_t z2[8];
  const uint32_t* zp = (const uint32_t*)(zs + idx * 16);
#pragma unroll
  for (int i = 0; i < 8; ++i) z2[i] = zp[i];
  uint32_t stv[16];
  const uint32_t* stp = (const uint32_t*)(state_t + idx * 32);
#pragma unroll
  for (int i = 0; i < 16; ++i) stv[i] = stp[i];

  float sqsum = 0.0f;
#pragma unroll 4
  for (int i = 0; i < 32; ++i) {
    float acc = s_pb[i];
#pragma unroll
    for (int kp = 0; kp < 8; ++kp) acc = fdot2(s_proj[kp * 32 + i], z2[kp], acc);
    f16x2 sv = __builtin_bit_cast(f16x2, stv[i >> 1]);
    float d = (float)sv[i & 1] - acc;
    sqsum += d * d;
  }

  float hd[16];
#pragma unroll
  for (int i = 0; i < 16; ++i) hd[i] = 0.0f;
#pragma unroll 2
  for (int j = 0; j < 128; ++j) {
    float a = s_ab[j];
#pragma unroll
    for (int kp = 0; kp < 8; ++kp) a = fdot2(s_act[kp * 128 + j], z2[kp], a);
    a = fmaxf(a, 0.0f);
#pragma unroll
    for (int p = 0; p < 8; ++p) {
      f16x2 w = __builtin_bit_cast(f16x2, s_head[j * 8 + p]);
      hd[2 * p] += (float)w[0] * a;
      hd[2 * p + 1] += (float)w[1] * a;
    }
  }
  const float* xp = xs + idx * 23;
  float dl0 = hd[0] - xp[18], dl1 = hd[1] - xp[19];
  float land = dl0 * dl0 + dl1 * dl1;
  float dm0 = hd[14] - xp[21], dm1 = hd[15] - xp[22];
  float move = dm0 * dm0 + dm1 * dm1;
  int sid = (int)xp[20];
  float m = hd[2];
#pragma unroll
  for (int s = 1; s < 12; ++s) m = fmaxf(m, hd[2 + s]);
  float sume = 0.0f;
#pragma unroll
  for (int s = 0; s < 12; ++s) sume += __expf(hd[2 + s] - m);
  float lse = m + __logf(sume);
  float pl = 0.0f;
#pragma unroll
  for (int s = 0; s < 12; ++s)
    if (s == sid) pl = hd[2 + s];
  float picked = 0.0f, cnt = 0.0f;
  if (sid != 0) {
    picked = pl - lse;
    cnt = 1.0f;
  }
  float vals[5] = {sqsum, land, move, picked, cnt};
#pragma unroll
  for (int v = 0; v < 5; ++v) {
    float x = vals[v];
    for (int off = 1; off < 64; off <<= 1) x += __shfl_xor(x, off);
    vals[v] = x;
  }
  int lane = tid & 63, wv = tid >> 6;
  if (lane == 0) {
#pragma unroll
    for (int v = 0; v < 5; ++v) s_red[wv * 5 + v] = vals[v];
  }
  __syncthreads();
  if (tid == 0) {
#pragma unroll
    for (int v = 0; v < 5; ++v) {
      float s = s_red[v] + s_red[5 + v] + s_red[10 + v] + s_red[15 + v];
      atomicAdd(&accums[v], s);
    }
  }
}

// ---------------------------------------------------------------------------
// Kernel 5: finalize the two scalar outputs.
// ---------------------------------------------------------------------------
__global__ void k_fin(const float* __restrict__ accums,
                      const float* __restrict__ noise_std,
                      float* __restrict__ out) {
  if (threadIdx.x == 0 && blockIdx.x == 0) {
    float sd = noise_std[0];
    float log_pxs = -0.5f * accums[0] / (sd * sd * (float)B_SZ) -
                    (float)T_STEPS * 32.0f * (logf(sd) + 0.5f * LOG2PI);
    float land = accums[1] / (float)(T_STEPS * B_SZ * 2);
    float move = accums[2] / (float)(T_STEPS * B_SZ * 2);
    float shot = -accums[3] / fmaxf(accums[4], 1.0f);
    float out1 = accums[5] / (float)B_SZ + accums[6] / (float)B_SZ + land + shot + move;
    out[0] = log_pxs;
    out[1] = out1;
  }
}

// ---------------------------------------------------------------------------
extern "C" void kernel_launch(void* const* d_in, const int* in_sizes, int n_in,
                              void* d_out, int out_size, void* d_ws,
                              size_t ws_size, hipStream_t stream) {
  const float* xs = (const float*)d_in[1];
  const float* ts = (const float*)d_in[2];
  const float* noise_std = (const float*)d_in[3];
  const float* z0_noise = (const float*)d_in[4];
  const float* bm_noise = (const float*)d_in[5];
  const float* shot_emb = (const float*)d_in[6];
  const float* player_emb = (const float*)d_in[7];
  const float* gru_wih = (const float*)d_in[8];
  const float* gru_whh = (const float*)d_in[9];
  const float* gru_bih = (const float*)d_in[10];
  const float* gru_bhh = (const float*)d_in[11];
  const float* enc_w = (const float*)d_in[12];
  const float* enc_b = (const float*)d_in[13];
  const float* qz0_w = (const float*)d_in[14];
  const float* qz0_b = (const float*)d_in[15];
  const float* f_w1 = (const float*)d_in[16];
  const float* f_b1 = (const float*)d_in[17];
  const float* f_w2 = (const float*)d_in[18];
  const float* f_b2 = (const float*)d_in[19];
  const float* f_w3 = (const float*)d_in[20];
  const float* f_b3 = (const float*)d_in[21];
  const float* h_w1 = (const float*)d_in[22];
  const float* h_b1 = (const float*)d_in[23];
  const float* h_w2 = (const float*)d_in[24];
  const float* h_b2 = (const float*)d_in[25];
  const float* h_w3 = (const float*)d_in[26];
  const float* h_b3 = (const float*)d_in[27];
  const float* g_w1 = (const float*)d_in[28];
  const float* g_b1 = (const float*)d_in[29];
  const float* g_w2 = (const float*)d_in[30];
  const float* g_b2 = (const float*)d_in[31];
  const float* proj_w = (const float*)d_in[32];
  const float* proj_b = (const float*)d_in[33];
  const float* pz0_mean = (const float*)d_in[34];
  const float* pz0_logstd = (const float*)d_in[35];
  const float* act_w = (const float*)d_in[36];
  const float* act_b = (const float*)d_in[37];
  const float* act_land_w = (const float*)d_in[38];
  const float* act_shot_w = (const float*)d_in[39];
  const float* act_move_w = (const float*)d_in[40];

  char* ws = (char*)d_ws;
  float* accums = (float*)ws;                       // 16 floats (256 B reserved)
  f16* state_t = (f16*)(ws + 256);                  // T*B*32 f16 = 16 MB
  f16* ctx = (f16*)(ws + 256 + 16777216);           // T*B*64 f16 = 32 MB
  float* z0b = (float*)(ws + 256 + 16777216 + 33554432);   // B*16 f32
  f16* zs = (f16*)(ws + 256 + 16777216 + 33554432 + 32768);  // T*B*16 f16 = 8 MB
  float* g_tab = (float*)(ws + 256 + 16777216 + 33554432 + 32768 + 8388608);  // 4 MB

  k_embed<<<1024, 256, 0, stream>>>(xs, shot_emb, player_emb, state_t, accums);
  k_gtab<<<4096, 256, 0, stream>>>(g_w1, g_b1, g_w2, g_b2, g_tab);
  k_gru<<<256, 512, 0, stream>>>(state_t, gru_wih, gru_whh, gru_bih, gru_bhh,
                                 enc_w, enc_b, qz0_w, qz0_b, z0_noise, pz0_mean,
                                 pz0_logstd, ctx, z0b, accums);
  k_sde<<<512, 256, 0, stream>>>(ctx, z0b, ts, bm_noise, f_w1, f_b1, f_w2, f_b2,
                                 f_w3, f_b3, h_w1, h_b1, h_w2, h_b2, h_w3, h_b3,
                                 g_tab, zs, accums);
  k_dec<<<1024, 256, 0, stream>>>(zs, state_t, xs, proj_w, proj_b, act_w, act_b,
                                  act_land_w, act_shot_w, act_move_w, accums);
  k_fin<<<1, 64, 0, stream>>>(accums, noise_std, (float*)d_out);
}

// Round 11
// 1628.061 us; speedup vs baseline: 1.3500x; 1.0027x over previous
//
#include <hip/hip_runtime.h>
#include <cstdint>

typedef _Float16 f16;
typedef _Float16 f16x2 __attribute__((ext_vector_type(2)));

#define T_STEPS 512
#define B_SZ 512
#define LOG2PI 1.8378770664093453f

// Raw barrier: drain LDS only (NOT vmcnt) so in-flight global prefetch loads
// and stores survive across the barrier.
__device__ __forceinline__ void barrier_lds() {
  asm volatile("s_waitcnt lgkmcnt(0)" ::: "memory");
  __builtin_amdgcn_s_barrier();
  asm volatile("" ::: "memory");
}

__device__ __forceinline__ uint32_t packh2(float a, float b) {
  f16x2 v; v[0] = (f16)a; v[1] = (f16)b;
  return __builtin_bit_cast(uint32_t, v);
}

__device__ __forceinline__ float fdot2(uint32_t a, uint32_t b, float c) {
#if defined(__AMDGCN__) && __has_builtin(__builtin_amdgcn_fdot2)
  return __builtin_amdgcn_fdot2(__builtin_bit_cast(f16x2, a),
                                __builtin_bit_cast(f16x2, b), c, false);
#else
  f16x2 x = __builtin_bit_cast(f16x2, a), y = __builtin_bit_cast(f16x2, b);
  return c + (float)x[0] * (float)y[0] + (float)x[1] * (float)y[1];
#endif
}

#define DOT4(acc, w0, w1, w2, w3, v)                                     \
  do {                                                                   \
    acc = fdot2((w0), (v).x, acc); acc = fdot2((w1), (v).y, acc);        \
    acc = fdot2((w2), (v).z, acc); acc = fdot2((w3), (v).w, acc);        \
  } while (0)

__device__ __forceinline__ float sigmoidf_(float x) {
  return 1.0f / (1.0f + __expf(-x));
}
__device__ __forceinline__ float tanhf_(float x) {
  float ax = fabsf(x);
  float t = __expf(-2.0f * ax);
  float r = (1.0f - t) / (1.0f + t);
  return copysignf(r, x);
}
__device__ __forceinline__ float softplusf_(float x) {
  return fmaxf(x, 0.0f) + __logf(1.0f + __expf(-fabsf(x)));
}

// ---------------------------------------------------------------------------
// Kernel 1: embedding / state_t construction.  state_t: (T,B,32) f16.
// ---------------------------------------------------------------------------
__global__ __launch_bounds__(256) void k_embed(
    const float* __restrict__ xs, const float* __restrict__ shot_emb,
    const float* __restrict__ player_emb, f16* __restrict__ state_t,
    float* __restrict__ accums) {
  if (blockIdx.x == 0 && threadIdx.x < 16) accums[threadIdx.x] = 0.0f;
  size_t idx = (size_t)blockIdx.x * 256 + threadIdx.x;
  const float* xp = xs + idx * 23;
  f16* op = state_t + idx * 32;
  int sid = (int)xp[12];
  int pid = (int)xp[17];
#pragma unroll
  for (int i = 0; i < 12; ++i) op[i] = (f16)xp[i];
  const float* se = shot_emb + sid * 8;
#pragma unroll
  for (int i = 0; i < 8; ++i) op[12 + i] = (f16)se[i];
#pragma unroll
  for (int i = 0; i < 4; ++i) op[20 + i] = (f16)xp[13 + i];
  const float* pe = player_emb + pid * 8;
#pragma unroll
  for (int i = 0; i < 8; ++i) op[24 + i] = (f16)pe[i];
}

// ---------------------------------------------------------------------------
// Kernel 1b: g-network lookup table (R6-verified).  16 x 65536 f32 = 4 MB.
// ---------------------------------------------------------------------------
__global__ __launch_bounds__(256) void k_gtab(
    const float* __restrict__ gw1, const float* __restrict__ gb1,
    const float* __restrict__ gw2, const float* __restrict__ gb2,
    float* __restrict__ g_tab) {
  int gid = blockIdx.x * 256 + threadIdx.x;
  int l = gid >> 16, yi = gid & 0xffff;
  f16 hy = __builtin_bit_cast(f16, (unsigned short)yi);
  float y = (float)hy;
  const float* w1 = gw1 + l * 128;
  const float* b1 = gb1 + l * 128;
  const float* w2 = gw2 + l * 128;
  float a0 = 0.f, a1 = 0.f;
#pragma unroll 8
  for (int h = 0; h < 128; h += 2) {
    a0 = fmaf(softplusf_(fmaf(y, w1[h], b1[h])), w2[h], a0);
    a1 = fmaf(softplusf_(fmaf(y, w1[h + 1], b1[h + 1])), w2[h + 1], a1);
  }
  g_tab[gid] = sigmoidf_(a0 + a1 + gb2[l]);
}

// ---------------------------------------------------------------------------
// Kernel 2: backward GRU scan + encoder + qz0 head.
// *** 512 blocks x 256 threads, ONE batch/block, 2 blocks/CU *** (the k_sde
// blueprint).  2 LDS-only barriers/step.  Phase A balanced at 136 fdot2 per
// thread: pair r = tid>>1 (hh = tid&1) computes half-rows of R[r], Z[r], N[r]
// (x-half 8 + h-half 32 each, h-half uint4s reused) + one enc quarter (16);
// shfl_xor(1) combines.  Phase B: h-update (tid<128, h_old in regs), ctx
// combine (tid 128..191), x stage (tid 252..255).
// ---------------------------------------------------------------------------
__global__ __launch_bounds__(256, 2) void k_gru(
    const f16* __restrict__ state_t, const float* __restrict__ wih,
    const float* __restrict__ whh, const float* __restrict__ bih,
    const float* __restrict__ bhh, const float* __restrict__ enc_w,
    const float* __restrict__ enc_b, const float* __restrict__ qz0_w,
    const float* __restrict__ qz0_b, const float* __restrict__ z0_noise,
    const float* __restrict__ pz0_mean, const float* __restrict__ pz0_logstd,
    f16* __restrict__ ctx, float* __restrict__ z0_out,
    float* __restrict__ accums) {
  __shared__ uint32_t s_x[16];       // x_t, f16x2 packed
  __shared__ uint32_t s_h[64];       // h,   f16x2 packed
  __shared__ float s_gates[128 * 4]; // [du][R,Z,iN,hN]
  __shared__ float s_encp[64 * 2];   // [c][ks]
  __shared__ float s_ctx0[64];
  __shared__ float s_q[32];

  const int tid = threadIdx.x;
  const int bg = blockIdx.x;          // batch element
  const int r = tid >> 1, hh = tid & 1;
  const int ec = r & 63, eks = r >> 6;   // enc task (c, ks) of pair r
  const uint32_t* stu = (const uint32_t*)state_t;

  // ---- weight preload (per-thread halves/quarters)
  uint32_t wR[32], wZ[32], wN[32];    // whh h-halves (rows r, 128+r, 256+r)
  uint32_t wRx[8], wZx[8], wNx[8];    // wih x-halves
  uint32_t wE[16];                    // enc quarter
  {
    const float* w0 = whh + (size_t)(0 * 128 + r) * 128 + hh * 64;
    const float* w1 = whh + (size_t)(1 * 128 + r) * 128 + hh * 64;
    const float* w2 = whh + (size_t)(2 * 128 + r) * 128 + hh * 64;
#pragma unroll
    for (int i = 0; i < 32; ++i) {
      wR[i] = packh2(w0[2 * i], w0[2 * i + 1]);
      wZ[i] = packh2(w1[2 * i], w1[2 * i + 1]);
      wN[i] = packh2(w2[2 * i], w2[2 * i + 1]);
    }
    const float* x0 = wih + (size_t)(0 * 128 + r) * 32 + hh * 16;
    const float* x1 = wih + (size_t)(1 * 128 + r) * 32 + hh * 16;
    const float* x2 = wih + (size_t)(2 * 128 + r) * 32 + hh * 16;
#pragma unroll
    for (int i = 0; i < 8; ++i) {
      wRx[i] = packh2(x0[2 * i], x0[2 * i + 1]);
      wZx[i] = packh2(x1[2 * i], x1[2 * i + 1]);
      wNx[i] = packh2(x2[2 * i], x2[2 * i + 1]);
    }
    const float* we = enc_w + (size_t)ec * 128 + eks * 64 + hh * 32;
#pragma unroll
    for (int i = 0; i < 16; ++i) wE[i] = packh2(we[2 * i], we[2 * i + 1]);
  }
  const float bR = bih[r] + bhh[r];
  const float bZ = bih[128 + r] + bhh[128 + r];
  const float bNi = bih[256 + r];
  const float bNh = bhh[256 + r];
  float encbr = 0.f;
  if (tid >= 128 && tid < 192) encbr = enc_b[tid - 128];

  float h_old = 0.0f;  // du = tid (threads 0..127)
  if (tid < 64) s_h[tid] = 0u;
  if (tid < 4)
    *(uint4*)&s_x[tid * 4] =
        *(const uint4*)(stu + ((size_t)(T_STEPS - 1) * B_SZ + bg) * 16 + tid * 4);
  __syncthreads();

  for (int t = T_STEPS - 1; t >= 0; --t) {
    uint4 xpref = make_uint4(0, 0, 0, 0);
    if (tid >= 252 && t > 0)
      xpref = *(const uint4*)(stu +
                              ((size_t)(t - 1) * B_SZ + bg) * 16 + (tid - 252) * 4);
    // ---- Phase A: paired half-row gate dots + enc quarter
    {
      const uint4* xq = (const uint4*)&s_x[hh * 8];
      uint4 xv0 = xq[0], xv1 = xq[1];
      const uint4* hq = (const uint4*)&s_h[hh * 32];
      float aR = 0.f, aZ = 0.f, aNi = 0.f, aNh = 0.f;
      DOT4(aR, wRx[0], wRx[1], wRx[2], wRx[3], xv0);
      DOT4(aR, wRx[4], wRx[5], wRx[6], wRx[7], xv1);
      DOT4(aZ, wZx[0], wZx[1], wZx[2], wZx[3], xv0);
      DOT4(aZ, wZx[4], wZx[5], wZx[6], wZx[7], xv1);
      DOT4(aNi, wNx[0], wNx[1], wNx[2], wNx[3], xv0);
      DOT4(aNi, wNx[4], wNx[5], wNx[6], wNx[7], xv1);
#pragma unroll
      for (int j = 0; j < 8; ++j) {
        uint4 hv = hq[j];
        DOT4(aR, wR[4 * j], wR[4 * j + 1], wR[4 * j + 2], wR[4 * j + 3], hv);
        DOT4(aZ, wZ[4 * j], wZ[4 * j + 1], wZ[4 * j + 2], wZ[4 * j + 3], hv);
        DOT4(aNh, wN[4 * j], wN[4 * j + 1], wN[4 * j + 2], wN[4 * j + 3], hv);
      }
      aR += __shfl_xor(aR, 1);
      aZ += __shfl_xor(aZ, 1);
      aNi += __shfl_xor(aNi, 1);
      aNh += __shfl_xor(aNh, 1);
      if (hh == 0) {
        s_gates[r * 4 + 0] = aR + bR;
        s_gates[r * 4 + 2] = aNi + bNi;
      } else {
        s_gates[r * 4 + 1] = aZ + bZ;
        s_gates[r * 4 + 3] = aNh + bNh;
      }
      if (t < T_STEPS - 1) {
        const uint4* eq = (const uint4*)&s_h[eks * 32 + hh * 16];
        float aE = 0.f;
#pragma unroll
        for (int j = 0; j < 4; ++j) {
          uint4 ev = eq[j];
          DOT4(aE, wE[4 * j], wE[4 * j + 1], wE[4 * j + 2], wE[4 * j + 3], ev);
        }
        aE += __shfl_xor(aE, 1);
        if (hh == 0) s_encp[ec * 2 + eks] = aE;
      }
    }
    barrier_lds();
    // ---- Phase B: h update; ctx combine; x stage
    if (tid < 128) {
      const float4 gt = *(const float4*)&s_gates[tid * 4];
      float rr = sigmoidf_(gt.x), zg = sigmoidf_(gt.y);
      float n = tanhf_(gt.z + rr * gt.w);
      float hnew = (1.0f - zg) * n + zg * h_old;
      h_old = hnew;
      ((f16*)&s_h[0])[tid] = (f16)hnew;
    } else if (tid < 192) {
      int c = tid - 128;
      if (t < T_STEPS - 1) {
        float v = s_encp[c * 2] + s_encp[c * 2 + 1] + encbr;
        ctx[((size_t)(t + 1) * B_SZ + bg) * 64 + c] = (f16)v;
      }
    }
    if (tid >= 252 && t > 0) *(uint4*)&s_x[(tid - 252) * 4] = xpref;
    barrier_lds();
  }

  // ---- Tail: enc(h(0)) -> ctx[0] + s_ctx0; qz0 head; z0 + KL
  {
    const uint4* eq = (const uint4*)&s_h[eks * 32 + hh * 16];
    float aE = 0.f;
#pragma unroll
    for (int j = 0; j < 4; ++j) {
      uint4 ev = eq[j];
      DOT4(aE, wE[4 * j], wE[4 * j + 1], wE[4 * j + 2], wE[4 * j + 3], ev);
    }
    aE += __shfl_xor(aE, 1);
    if (hh == 0) s_encp[ec * 2 + eks] = aE;
  }
  __syncthreads();
  if (tid < 64) {
    float v = s_encp[tid * 2] + s_encp[tid * 2 + 1] + enc_b[tid];
    ctx[(size_t)bg * 64 + tid] = (f16)v;
    s_ctx0[tid] = v;
  }
  __syncthreads();
  if (tid < 32) {
    float acc = qz0_b[tid];
#pragma unroll 8
    for (int k = 0; k < 64; ++k) acc += qz0_w[tid * 64 + k] * s_ctx0[k];
    s_q[tid] = acc;
  }
  __syncthreads();
  if (tid < 16) {
    float qm = s_q[tid], qls = s_q[16 + tid];
    float z0v = qm + __expf(qls) * z0_noise[bg * 16 + tid];
    z0_out[bg * 16 + tid] = z0v;
    float pm = pz0_mean[tid], pls = pz0_logstd[tid];
    float var_q = __expf(2.0f * qls);
    float var_p = __expf(2.0f * pls);
    float dm = qm - pm;
    float kl = pls - qls + (var_q + dm * dm) / (2.0f * var_p) - 0.5f;
    atomicAdd(&accums[5], kl);
  }
}

// ---------------------------------------------------------------------------
// Kernel 3: SDE scan.  (R10-verified: 797 us)  512 blocks x 256 threads,
// 1 batch/block, 2 blocks/CU, 3 LDS-only barriers/step, balanced phases,
// g-network via table lookup.
// ---------------------------------------------------------------------------
__global__ __launch_bounds__(256, 2) void k_sde(
    const f16* __restrict__ ctx, const float* __restrict__ z0_in,
    const float* __restrict__ ts, const float* __restrict__ bm_noise,
    const float* __restrict__ fw1, const float* __restrict__ fb1,
    const float* __restrict__ fw2, const float* __restrict__ fb2,
    const float* __restrict__ fw3, const float* __restrict__ fb3,
    const float* __restrict__ hw1, const float* __restrict__ hb1,
    const float* __restrict__ hw2, const float* __restrict__ hb2,
    const float* __restrict__ hw3, const float* __restrict__ hb3,
    const float* __restrict__ g_tab,
    f16* __restrict__ zs, float* __restrict__ accums) {
  __shared__ uint32_t s_x2[40];       // [z(8 u32) | ctx(32 u32)] f16x2
  __shared__ uint32_t s_h1[2][64];    // [mlp] layer-1 act, f16x2
  __shared__ uint32_t s_h2[2][64];    // [mlp] layer-2 act, f16x2
  __shared__ float s_dts[T_STEPS];

  const int tid = threadIdx.x;
  const int bg = blockIdx.x;
  const uint4* ctx4 = (const uint4*)ctx;

  const int r1 = tid >> 1, hh = tid & 1;
  const int mlp2 = tid >> 7, u2 = tid & 127;
  const int l3 = (tid >> 3) & 15;
  const int mlp3 = (tid >> 2) & 1;
  const int kq = tid & 3;
  const bool p3act = (tid < 128);
  const bool zlane = p3act && ((tid & 7) == 0);
  const bool stg = (tid >= 128 && tid < 136);

  // ---- weight preload
  uint32_t uw1f[20], uw1h[4], wP2[64], wP3[16];
  float bf1r, bh1r, bias2r, fb3r = 0.f, hb3r = 0.f;
  {
    const float* w = fw1 + (size_t)r1 * 80 + hh * 40;
#pragma unroll
    for (int i = 0; i < 20; ++i) uw1f[i] = packh2(w[2 * i], w[2 * i + 1]);
    bf1r = fb1[r1];
  }
  {
    const float* w = hw1 + (size_t)r1 * 16 + hh * 8;
#pragma unroll
    for (int i = 0; i < 4; ++i) uw1h[i] = packh2(w[2 * i], w[2 * i + 1]);
    bh1r = hb1[r1];
  }
  {
    const float* w = (mlp2 ? hw2 : fw2) + (size_t)u2 * 128;
#pragma unroll
    for (int i = 0; i < 64; ++i) wP2[i] = packh2(w[2 * i], w[2 * i + 1]);
    bias2r = (mlp2 ? hb2 : fb2)[u2];
  }
  if (p3act) {
    const float* w = (mlp3 ? hw3 : fw3) + (size_t)l3 * 128 + kq * 32;
#pragma unroll
    for (int i = 0; i < 16; ++i) wP3[i] = packh2(w[2 * i], w[2 * i + 1]);
    fb3r = fb3[l3];
    hb3r = hb3[l3];
  }
  for (int i = tid; i < T_STEPS - 1; i += 256) s_dts[i] = ts[i + 1] - ts[i];

  // ---- state init
  float zreg = 0.f, bmc = 0.f, path_acc = 0.f;
  uint4 cpref = make_uint4(0, 0, 0, 0);
  if (zlane) {
    zreg = z0_in[bg * 16 + l3];
    ((f16*)&s_x2[0])[l3] = (f16)zreg;
    zs[(size_t)bg * 16 + l3] = (f16)zreg;
    bmc = bm_noise[(size_t)bg * 16 + l3];
  }
  if (stg) {
    int q = tid - 128;
    uint4 v = ctx4[((size_t)1 * B_SZ + bg) * 8 + q];
    *(uint4*)&s_x2[8 + q * 4] = v;
  }
  __syncthreads();

  for (int t = 0; t < T_STEPS - 1; ++t) {
    float bmn = 0.f, gvp = 0.f;
    if (zlane) {
      unsigned short zb = __builtin_bit_cast(unsigned short, (f16)zreg);
      gvp = g_tab[l3 * 65536 + (int)zb];
      if (t < T_STEPS - 2)
        bmn = bm_noise[((size_t)(t + 1) * B_SZ + bg) * 16 + l3];
    }
    if (stg && t <= T_STEPS - 3)
      cpref = ctx4[((size_t)(t + 2) * B_SZ + bg) * 8 + (tid - 128)];

    // ---- P1: L1 balanced half-rows (all 256 threads)
    {
      const uint4* xq = (const uint4*)&s_x2[0];
      const int base = hh * 5;
      float a0 = 0.f, a1 = 0.f;
      {
        uint4 v0 = xq[base + 0], v1 = xq[base + 1];
        DOT4(a0, uw1f[0], uw1f[1], uw1f[2], uw1f[3], v0);
        DOT4(a1, uw1f[4], uw1f[5], uw1f[6], uw1f[7], v1);
        uint4 v2 = xq[base + 2], v3 = xq[base + 3];
        DOT4(a0, uw1f[8], uw1f[9], uw1f[10], uw1f[11], v2);
        DOT4(a1, uw1f[12], uw1f[13], uw1f[14], uw1f[15], v3);
        uint4 v4 = xq[base + 4];
        DOT4(a0, uw1f[16], uw1f[17], uw1f[18], uw1f[19], v4);
      }
      float af = a0 + a1;
      uint4 vz = xq[hh];
      float ah = 0.f;
      DOT4(ah, uw1h[0], uw1h[1], uw1h[2], uw1h[3], vz);
      float ff = af + __shfl_xor(af, 1);
      float fh = ah + __shfl_xor(ah, 1);
      if (hh == 0)
        ((f16*)&s_h1[0][0])[r1] = (f16)softplusf_(ff + bf1r);
      else
        ((f16*)&s_h1[1][0])[r1] = (f16)softplusf_(fh + bh1r);
    }
    barrier_lds();
    // ---- P2: L2 full rows (all 256 threads)
    {
      const uint4* hq = (const uint4*)&s_h1[mlp2][0];
      float a0 = 0.f, a1 = 0.f;
#pragma unroll
      for (int j = 0; j < 16; j += 2) {
        uint4 v0 = hq[j], v1 = hq[j + 1];
        DOT4(a0, wP2[4 * j], wP2[4 * j + 1], wP2[4 * j + 2], wP2[4 * j + 3], v0);
        DOT4(a1, wP2[4 * j + 4], wP2[4 * j + 5], wP2[4 * j + 6], wP2[4 * j + 7], v1);
      }
      ((f16*)&s_h2[mlp2][0])[u2] = (f16)softplusf_(a0 + a1 + bias2r);
    }
    barrier_lds();
    // ---- P3: L3 quarter-rows over 2 waves + z update; ctx stage
    if (p3act) {
      const uint4* hq = (const uint4*)&s_h2[mlp3][kq * 16];
      float a0 = 0.f, a1 = 0.f;
#pragma unroll
      for (int j = 0; j < 4; j += 2) {
        uint4 v0 = hq[j], v1 = hq[j + 1];
        DOT4(a0, wP3[4 * j], wP3[4 * j + 1], wP3[4 * j + 2], wP3[4 * j + 3], v0);
        DOT4(a1, wP3[4 * j + 4], wP3[4 * j + 5], wP3[4 * j + 6], wP3[4 * j + 7], v1);
      }
      float a = a0 + a1;
      float s1 = a + __shfl_xor(a, 1);
      float s2 = s1 + __shfl_xor(s1, 2);
      float other = __shfl_xor(s2, 4);
      if ((tid & 7) == 0) {
        float fv = s2 + fb3r;
        float hv = other + hb3r;
        float gv = gvp;
        float dt = s_dts[t];
        float u_ = (fv - hv) / gv;
        float ls = u_ * u_;
        ls += __shfl_xor(ls, 8);
        ls += __shfl_xor(ls, 16);
        ls += __shfl_xor(ls, 32);
        if ((tid & 63) == 0) path_acc += 0.5f * ls * dt;
        float dw = sqrtf(dt) * bmc;
        float zn = zreg + fv * dt + gv * dw;
        zreg = zn;
        ((f16*)&s_x2[0])[l3] = (f16)zn;
        zs[((size_t)(t + 1) * B_SZ + bg) * 16 + l3] = (f16)zn;
        bmc = bmn;
      }
    } else if (stg && t <= T_STEPS - 3) {
      *(uint4*)&s_x2[8 + (tid - 128) * 4] = cpref;
    }
    barrier_lds();
  }
  if (tid == 0 || tid == 64) atomicAdd(&accums[6], path_acc);
}

// ---------------------------------------------------------------------------
// Kernel 4: decoder + losses.  One thread per (t,b).
// ---------------------------------------------------------------------------
__global__ __launch_bounds__(256) void k_dec(
    const f16* __restrict__ zs, const f16* __restrict__ state_t,
    const float* __restrict__ xs, const float* __restrict__ proj_w,
    const float* __restrict__ proj_b, const float* __restrict__ act_w,
    const float* __restrict__ act_b, const float* __restrict__ land_w,
    const float* __restrict__ shot_w, const float* __restrict__ move_w,
    float* __restrict__ accums) {
  __shared__ uint32_t s_proj[8 * 32];
  __shared__ uint32_t s_act[8 * 128];
  __shared__ uint32_t s_head[128 * 8];
  __shared__ float s_pb[32], s_ab[128];
  __shared__ float s_red[4 * 5];

  const int tid = threadIdx.x;
  for (int id = tid; id < 8 * 32; id += 256) {
    int kp = id & 7, n = id >> 3;
    s_proj[kp * 32 + n] = packh2(proj_w[n * 16 + 2 * kp], proj_w[n * 16 + 2 * kp + 1]);
  }
  for (int id = tid; id < 8 * 128; id += 256) {
    int kp = id & 7, n = id >> 3;
    s_act[kp * 128 + n] = packh2(act_w[n * 16 + 2 * kp], act_w[n * 16 + 2 * kp + 1]);
  }
  for (int id = tid; id < 128 * 8; id += 256) {
    int j = id >> 3, p = id & 7;
    int h0 = 2 * p, h1 = 2 * p + 1;
    float w0 = (h0 < 2) ? land_w[h0 * 128 + j]
                        : (h0 < 14 ? shot_w[(h0 - 2) * 128 + j]
                                   : move_w[(h0 - 14) * 128 + j]);
    float w1 = (h1 < 2) ? land_w[h1 * 128 + j]
                        : (h1 < 14 ? shot_w[(h1 - 2) * 128 + j]
                                   : move_w[(h1 - 14) * 128 + j]);
    s_head[j * 8 + p] = packh2(w0, w1);
  }
  if (tid < 32) s_pb[tid] = proj_b[tid];
  if (tid < 128) s_ab[tid] = act_b[tid];
  __syncthreads();

  size_t idx = (size_t)blockIdx.x * 256 + tid;
  uint32_t z2[8];
  const uint32_t* zp = (const uint32_t*)(zs + idx * 16);
#pragma unroll
  for (int i = 0; i < 8; ++i) z2[i] = zp[i];
  uint32_t stv[16];
  const uint32_t* stp = (const uint32_t*)(state_t + idx * 32);
#pragma unroll
  for (int i = 0; i < 16; ++i) stv[i] = stp[i];

  float sqsum = 0.0f;
#pragma unroll 4
  for (int i = 0; i < 32; ++i) {
    float acc = s_pb[i];
#pragma unroll
    for (int kp = 0; kp < 8; ++kp) acc = fdot2(s_proj[kp * 32 + i], z2[kp], acc);
    f16x2 sv = __builtin_bit_cast(f16x2, stv[i >> 1]);
    float d = (float)sv[i & 1] - acc;
    sqsum += d * d;
  }

  float hd[16];
#pragma unroll
  for (int i = 0; i < 16; ++i) hd[i] = 0.0f;
#pragma unroll 2
  for (int j = 0; j < 128; ++j) {
    float a = s_ab[j];
#pragma unroll
    for (int kp = 0; kp < 8; ++kp) a = fdot2(s_act[kp * 128 + j], z2[kp], a);
    a = fmaxf(a, 0.0f);
#pragma unroll
    for (int p = 0; p < 8; ++p) {
      f16x2 w = __builtin_bit_cast(f16x2, s_head[j * 8 + p]);
      hd[2 * p] += (float)w[0] * a;
      hd[2 * p + 1] += (float)w[1] * a;
    }
  }
  const float* xp = xs + idx * 23;
  float dl0 = hd[0] - xp[18], dl1 = hd[1] - xp[19];
  float land = dl0 * dl0 + dl1 * dl1;
  float dm0 = hd[14] - xp[21], dm1 = hd[15] - xp[22];
  float move = dm0 * dm0 + dm1 * dm1;
  int sid = (int)xp[20];
  float m = hd[2];
#pragma unroll
  for (int s = 1; s < 12; ++s) m = fmaxf(m, hd[2 + s]);
  float sume = 0.0f;
#pragma unroll
  for (int s = 0; s < 12; ++s) sume += __expf(hd[2 + s] - m);
  float lse = m + __logf(sume);
  float pl = 0.0f;
#pragma unroll
  for (int s = 0; s < 12; ++s)
    if (s == sid) pl = hd[2 + s];
  float picked = 0.0f, cnt = 0.0f;
  if (sid != 0) {
    picked = pl - lse;
    cnt = 1.0f;
  }
  float vals[5] = {sqsum, land, move, picked, cnt};
#pragma unroll
  for (int v = 0; v < 5; ++v) {
    float x = vals[v];
    for (int off = 1; off < 64; off <<= 1) x += __shfl_xor(x, off);
    vals[v] = x;
  }
  int lane = tid & 63, wv = tid >> 6;
  if (lane == 0) {
#pragma unroll
    for (int v = 0; v < 5; ++v) s_red[wv * 5 + v] = vals[v];
  }
  __syncthreads();
  if (tid == 0) {
#pragma unroll
    for (int v = 0; v < 5; ++v) {
      float s = s_red[v] + s_red[5 + v] + s_red[10 + v] + s_red[15 + v];
      atomicAdd(&accums[v], s);
    }
  }
}

// ---------------------------------------------------------------------------
// Kernel 5: finalize the two scalar outputs.
// ---------------------------------------------------------------------------
__global__ void k_fin(const float* __restrict__ accums,
                      const float* __restrict__ noise_std,
                      float* __restrict__ out) {
  if (threadIdx.x == 0 && blockIdx.x == 0) {
    float sd = noise_std[0];
    float log_pxs = -0.5f * accums[0] / (sd * sd * (float)B_SZ) -
                    (float)T_STEPS * 32.0f * (logf(sd) + 0.5f * LOG2PI);
    float land = accums[1] / (float)(T_STEPS * B_SZ * 2);
    float move = accums[2] / (float)(T_STEPS * B_SZ * 2);
    float shot = -accums[3] / fmaxf(accums[4], 1.0f);
    float out1 = accums[5] / (float)B_SZ + accums[6] / (float)B_SZ + land + shot + move;
    out[0] = log_pxs;
    out[1] = out1;
  }
}

// ---------------------------------------------------------------------------
extern "C" void kernel_launch(void* const* d_in, const int* in_sizes, int n_in,
                              void* d_out, int out_size, void* d_ws,
                              size_t ws_size, hipStream_t stream) {
  const float* xs = (const float*)d_in[1];
  const float* ts = (const float*)d_in[2];
  const float* noise_std = (const float*)d_in[3];
  const float* z0_noise = (const float*)d_in[4];
  const float* bm_noise = (const float*)d_in[5];
  const float* shot_emb = (const float*)d_in[6];
  const float* player_emb = (const float*)d_in[7];
  const float* gru_wih = (const float*)d_in[8];
  const float* gru_whh = (const float*)d_in[9];
  const float* gru_bih = (const float*)d_in[10];
  const float* gru_bhh = (const float*)d_in[11];
  const float* enc_w = (const float*)d_in[12];
  const float* enc_b = (const float*)d_in[13];
  const float* qz0_w = (const float*)d_in[14];
  const float* qz0_b = (const float*)d_in[15];
  const float* f_w1 = (const float*)d_in[16];
  const float* f_b1 = (const float*)d_in[17];
  const float* f_w2 = (const float*)d_in[18];
  const float* f_b2 = (const float*)d_in[19];
  const float* f_w3 = (const float*)d_in[20];
  const float* f_b3 = (const float*)d_in[21];
  const float* h_w1 = (const float*)d_in[22];
  const float* h_b1 = (const float*)d_in[23];
  const float* h_w2 = (const float*)d_in[24];
  const float* h_b2 = (const float*)d_in[25];
  const float* h_w3 = (const float*)d_in[26];
  const float* h_b3 = (const float*)d_in[27];
  const float* g_w1 = (const float*)d_in[28];
  const float* g_b1 = (const float*)d_in[29];
  const float* g_w2 = (const float*)d_in[30];
  const float* g_b2 = (const float*)d_in[31];
  const float* proj_w = (const float*)d_in[32];
  const float* proj_b = (const float*)d_in[33];
  const float* pz0_mean = (const float*)d_in[34];
  const float* pz0_logstd = (const float*)d_in[35];
  const float* act_w = (const float*)d_in[36];
  const float* act_b = (const float*)d_in[37];
  const float* act_land_w = (const float*)d_in[38];
  const float* act_shot_w = (const float*)d_in[39];
  const float* act_move_w = (const float*)d_in[40];

  char* ws = (char*)d_ws;
  float* accums = (float*)ws;                       // 16 floats (256 B reserved)
  f16* state_t = (f16*)(ws + 256);                  // T*B*32 f16 = 16 MB
  f16* ctx = (f16*)(ws + 256 + 16777216);           // T*B*64 f16 = 32 MB
  float* z0b = (float*)(ws + 256 + 16777216 + 33554432);   // B*16 f32
  f16* zs = (f16*)(ws + 256 + 16777216 + 33554432 + 32768);  // T*B*16 f16 = 8 MB
  float* g_tab = (float*)(ws + 256 + 16777216 + 33554432 + 32768 + 8388608);  // 4 MB

  k_embed<<<1024, 256, 0, stream>>>(xs, shot_emb, player_emb, state_t, accums);
  k_gtab<<<4096, 256, 0, stream>>>(g_w1, g_b1, g_w2, g_b2, g_tab);
  k_gru<<<512, 256, 0, stream>>>(state_t, gru_wih, gru_whh, gru_bih, gru_bhh,
                                 enc_w, enc_b, qz0_w, qz0_b, z0_noise, pz0_mean,
                                 pz0_logstd, ctx, z0b, accums);
  k_sde<<<512, 256, 0, stream>>>(ctx, z0b, ts, bm_noise, f_w1, f_b1, f_w2, f_b2,
                                 f_w3, f_b3, h_w1, h_b1, h_w2, h_b2, h_w3, h_b3,
                                 g_tab, zs, accums);
  k_dec<<<1024, 256, 0, stream>>>(zs, state_t, xs, proj_w, proj_b, act_w, act_b,
                                  act_land_w, act_shot_w, act_move_w, accums);
  k_fin<<<1, 64, 0, stream>>>(accums, noise_std, (float*)d_out);
}

// Round 12
// 1616.396 us; speedup vs baseline: 1.3598x; 1.0072x over previous
//
#include <hip/hip_runtime.h>
#include <cstdint>

typedef _Float16 f16;
typedef _Float16 f16x2 __attribute__((ext_vector_type(2)));

#define T_STEPS 512
#define B_SZ 512
#define LOG2PI 1.8378770664093453f

// Raw barrier: drain LDS only (NOT vmcnt) so in-flight global prefetch loads
// and stores survive across the barrier.
__device__ __forceinline__ void barrier_lds() {
  asm volatile("s_waitcnt lgkmcnt(0)" ::: "memory");
  __builtin_amdgcn_s_barrier();
  asm volatile("" ::: "memory");
}

__device__ __forceinline__ uint32_t packh2(float a, float b) {
  f16x2 v; v[0] = (f16)a; v[1] = (f16)b;
  return __builtin_bit_cast(uint32_t, v);
}

__device__ __forceinline__ float fdot2(uint32_t a, uint32_t b, float c) {
#if defined(__AMDGCN__) && __has_builtin(__builtin_amdgcn_fdot2)
  return __builtin_amdgcn_fdot2(__builtin_bit_cast(f16x2, a),
                                __builtin_bit_cast(f16x2, b), c, false);
#else
  f16x2 x = __builtin_bit_cast(f16x2, a), y = __builtin_bit_cast(f16x2, b);
  return c + (float)x[0] * (float)y[0] + (float)x[1] * (float)y[1];
#endif
}

#define DOT4(acc, w0, w1, w2, w3, v)                                     \
  do {                                                                   \
    acc = fdot2((w0), (v).x, acc); acc = fdot2((w1), (v).y, acc);        \
    acc = fdot2((w2), (v).z, acc); acc = fdot2((w3), (v).w, acc);        \
  } while (0)

__device__ __forceinline__ float sigmoidf_(float x) {
  return 1.0f / (1.0f + __expf(-x));
}
__device__ __forceinline__ float tanhf_(float x) {
  float ax = fabsf(x);
  float t = __expf(-2.0f * ax);
  float r = (1.0f - t) / (1.0f + t);
  return copysignf(r, x);
}
__device__ __forceinline__ float softplusf_(float x) {
  return fmaxf(x, 0.0f) + __logf(1.0f + __expf(-fabsf(x)));
}

// ---------------------------------------------------------------------------
// Kernel 1: embedding / state_t construction.  state_t: (T,B,32) f16.
// ---------------------------------------------------------------------------
__global__ __launch_bounds__(256) void k_embed(
    const float* __restrict__ xs, const float* __restrict__ shot_emb,
    const float* __restrict__ player_emb, f16* __restrict__ state_t,
    float* __restrict__ accums) {
  if (blockIdx.x == 0 && threadIdx.x < 16) accums[threadIdx.x] = 0.0f;
  size_t idx = (size_t)blockIdx.x * 256 + threadIdx.x;
  const float* xp = xs + idx * 23;
  f16* op = state_t + idx * 32;
  int sid = (int)xp[12];
  int pid = (int)xp[17];
#pragma unroll
  for (int i = 0; i < 12; ++i) op[i] = (f16)xp[i];
  const float* se = shot_emb + sid * 8;
#pragma unroll
  for (int i = 0; i < 8; ++i) op[12 + i] = (f16)se[i];
#pragma unroll
  for (int i = 0; i < 4; ++i) op[20 + i] = (f16)xp[13 + i];
  const float* pe = player_emb + pid * 8;
#pragma unroll
  for (int i = 0; i < 8; ++i) op[24 + i] = (f16)pe[i];
}

// ---------------------------------------------------------------------------
// Kernel 1b: g-network lookup table (R6-verified).  16 x 65536 f32 = 4 MB.
// ---------------------------------------------------------------------------
__global__ __launch_bounds__(256) void k_gtab(
    const float* __restrict__ gw1, const float* __restrict__ gb1,
    const float* __restrict__ gw2, const float* __restrict__ gb2,
    float* __restrict__ g_tab) {
  int gid = blockIdx.x * 256 + threadIdx.x;
  int l = gid >> 16, yi = gid & 0xffff;
  f16 hy = __builtin_bit_cast(f16, (unsigned short)yi);
  float y = (float)hy;
  const float* w1 = gw1 + l * 128;
  const float* b1 = gb1 + l * 128;
  const float* w2 = gw2 + l * 128;
  float a0 = 0.f, a1 = 0.f;
#pragma unroll 8
  for (int h = 0; h < 128; h += 2) {
    a0 = fmaf(softplusf_(fmaf(y, w1[h], b1[h])), w2[h], a0);
    a1 = fmaf(softplusf_(fmaf(y, w1[h + 1], b1[h + 1])), w2[h + 1], a1);
  }
  g_tab[gid] = sigmoidf_(a0 + a1 + gb2[l]);
}

// ---------------------------------------------------------------------------
// Kernel 2: backward GRU scan + encoder + qz0 head.
// 512 blocks x 256 threads, 1 batch/block, 2 blocks/CU.
// *** ONE LDS-only barrier per step ***.  Double-buffered s_h/s_x.
// Pair r = tid>>1 (hh = tid&1): half-rows of R,Z,N (24 x-dots + 96 h-dots);
// after shfl_xor(1) combines BOTH threads hold all four gate values -> the
// h-update is computed in-phase (pair-duplicated, tiny) and written to
// s_h[wb] while all reads use s_h[rb].  Enc rows as quads (c=tid>>2,
// ks=(tid>>1)&1): shfl_xor(1)+shfl_xor(2) combine, quad leader stores ctx
// directly.  s_gates / s_encp / phase B DELETED.  x prefetched one full
// step ahead in registers.
// ---------------------------------------------------------------------------
__global__ __launch_bounds__(256, 2) void k_gru(
    const f16* __restrict__ state_t, const float* __restrict__ wih,
    const float* __restrict__ whh, const float* __restrict__ bih,
    const float* __restrict__ bhh, const float* __restrict__ enc_w,
    const float* __restrict__ enc_b, const float* __restrict__ qz0_w,
    const float* __restrict__ qz0_b, const float* __restrict__ z0_noise,
    const float* __restrict__ pz0_mean, const float* __restrict__ pz0_logstd,
    f16* __restrict__ ctx, float* __restrict__ z0_out,
    float* __restrict__ accums) {
  __shared__ uint32_t s_x[2][16];    // [buf] x_t, f16x2 packed
  __shared__ uint32_t s_h[2][64];    // [buf] h,   f16x2 packed
  __shared__ float s_ctx0[64];
  __shared__ float s_q[32];

  const int tid = threadIdx.x;
  const int bg = blockIdx.x;              // batch element
  const int r = tid >> 1, hh = tid & 1;   // gate pair
  const int ec = tid >> 2, eks = (tid >> 1) & 1;  // enc quad
  const uint32_t* stu = (const uint32_t*)state_t;

  // ---- weight preload (per-thread halves/quarters)
  uint32_t wR[32], wZ[32], wN[32];    // whh h-halves (rows r, 128+r, 256+r)
  uint32_t wRx[8], wZx[8], wNx[8];    // wih x-halves
  uint32_t wE[16];                    // enc quarter (row ec, k-slice eks/hh)
  {
    const float* w0 = whh + (size_t)(0 * 128 + r) * 128 + hh * 64;
    const float* w1 = whh + (size_t)(1 * 128 + r) * 128 + hh * 64;
    const float* w2 = whh + (size_t)(2 * 128 + r) * 128 + hh * 64;
#pragma unroll
    for (int i = 0; i < 32; ++i) {
      wR[i] = packh2(w0[2 * i], w0[2 * i + 1]);
      wZ[i] = packh2(w1[2 * i], w1[2 * i + 1]);
      wN[i] = packh2(w2[2 * i], w2[2 * i + 1]);
    }
    const float* x0 = wih + (size_t)(0 * 128 + r) * 32 + hh * 16;
    const float* x1 = wih + (size_t)(1 * 128 + r) * 32 + hh * 16;
    const float* x2 = wih + (size_t)(2 * 128 + r) * 32 + hh * 16;
#pragma unroll
    for (int i = 0; i < 8; ++i) {
      wRx[i] = packh2(x0[2 * i], x0[2 * i + 1]);
      wZx[i] = packh2(x1[2 * i], x1[2 * i + 1]);
      wNx[i] = packh2(x2[2 * i], x2[2 * i + 1]);
    }
    const float* we = enc_w + (size_t)ec * 128 + eks * 64 + hh * 32;
#pragma unroll
    for (int i = 0; i < 16; ++i) wE[i] = packh2(we[2 * i], we[2 * i + 1]);
  }
  const float bR = bih[r] + bhh[r];
  const float bZ = bih[128 + r] + bhh[128 + r];
  const float bNi = bih[256 + r];
  const float bNh = bhh[256 + r];
  const float encbc = enc_b[ec];

  float h_old = 0.0f;  // h[r], replicated in pair (deterministic)
  if (tid < 64) s_h[0][tid] = 0u;
  if (tid < 4)
    *(uint4*)&s_x[0][tid * 4] =
        *(const uint4*)(stu + ((size_t)(T_STEPS - 1) * B_SZ + bg) * 16 + tid * 4);
  uint4 xpref = make_uint4(0, 0, 0, 0);
  if (tid >= 252)
    xpref = *(const uint4*)(stu +
                            ((size_t)(T_STEPS - 2) * B_SZ + bg) * 16 + (tid - 252) * 4);
  __syncthreads();

  for (int t = T_STEPS - 1; t >= 0; --t) {
    const int rb = (t + 1) & 1, wb = t & 1;
    // ---- x stage (reg -> other buffer) + issue next prefetch
    if (tid >= 252) {
      if (t > 0) *(uint4*)&s_x[wb][(tid - 252) * 4] = xpref;
      if (t > 1)
        xpref = *(const uint4*)(stu +
                                ((size_t)(t - 2) * B_SZ + bg) * 16 + (tid - 252) * 4);
    }
    // ---- gates (half-rows) + in-phase h-update
    {
      const uint4* xq = (const uint4*)&s_x[rb][hh * 8];
      uint4 xv0 = xq[0], xv1 = xq[1];
      const uint4* hq = (const uint4*)&s_h[rb][hh * 32];
      float aR = 0.f, aZ = 0.f, aNi = 0.f, aNh = 0.f;
      DOT4(aR, wRx[0], wRx[1], wRx[2], wRx[3], xv0);
      DOT4(aR, wRx[4], wRx[5], wRx[6], wRx[7], xv1);
      DOT4(aZ, wZx[0], wZx[1], wZx[2], wZx[3], xv0);
      DOT4(aZ, wZx[4], wZx[5], wZx[6], wZx[7], xv1);
      DOT4(aNi, wNx[0], wNx[1], wNx[2], wNx[3], xv0);
      DOT4(aNi, wNx[4], wNx[5], wNx[6], wNx[7], xv1);
#pragma unroll
      for (int j = 0; j < 8; ++j) {
        uint4 hv = hq[j];
        DOT4(aR, wR[4 * j], wR[4 * j + 1], wR[4 * j + 2], wR[4 * j + 3], hv);
        DOT4(aZ, wZ[4 * j], wZ[4 * j + 1], wZ[4 * j + 2], wZ[4 * j + 3], hv);
        DOT4(aNh, wN[4 * j], wN[4 * j + 1], wN[4 * j + 2], wN[4 * j + 3], hv);
      }
      aR += __shfl_xor(aR, 1);
      aZ += __shfl_xor(aZ, 1);
      aNi += __shfl_xor(aNi, 1);
      aNh += __shfl_xor(aNh, 1);
      float rr = sigmoidf_(aR + bR);
      float zg = sigmoidf_(aZ + bZ);
      float n = tanhf_(aNi + bNi + rr * (aNh + bNh));
      float hnew = (1.0f - zg) * n + zg * h_old;
      h_old = hnew;
      if (hh == 0) ((f16*)&s_h[wb][0])[r] = (f16)hnew;
    }
    // ---- enc quad -> ctx[t+1] (reads h(t+1) = s_h[rb])
    if (t < T_STEPS - 1) {
      const uint4* eq = (const uint4*)&s_h[rb][eks * 32 + hh * 16];
      float aE = 0.f;
#pragma unroll
      for (int j = 0; j < 4; ++j) {
        uint4 ev = eq[j];
        DOT4(aE, wE[4 * j], wE[4 * j + 1], wE[4 * j + 2], wE[4 * j + 3], ev);
      }
      aE += __shfl_xor(aE, 1);
      aE += __shfl_xor(aE, 2);
      if ((tid & 3) == 0)
        ctx[((size_t)(t + 1) * B_SZ + bg) * 64 + ec] = (f16)(aE + encbc);
    }
    barrier_lds();
  }

  // ---- Tail: enc(h(0)) (in s_h[0], last write at t=0) -> ctx[0] + s_ctx0
  {
    const uint4* eq = (const uint4*)&s_h[0][eks * 32 + hh * 16];
    float aE = 0.f;
#pragma unroll
    for (int j = 0; j < 4; ++j) {
      uint4 ev = eq[j];
      DOT4(aE, wE[4 * j], wE[4 * j + 1], wE[4 * j + 2], wE[4 * j + 3], ev);
    }
    aE += __shfl_xor(aE, 1);
    aE += __shfl_xor(aE, 2);
    if ((tid & 3) == 0) {
      float v = aE + encbc;
      ctx[(size_t)bg * 64 + ec] = (f16)v;
      s_ctx0[ec] = v;
    }
  }
  __syncthreads();
  if (tid < 32) {
    float acc = qz0_b[tid];
#pragma unroll 8
    for (int k = 0; k < 64; ++k) acc += qz0_w[tid * 64 + k] * s_ctx0[k];
    s_q[tid] = acc;
  }
  __syncthreads();
  if (tid < 16) {
    float qm = s_q[tid], qls = s_q[16 + tid];
    float z0v = qm + __expf(qls) * z0_noise[bg * 16 + tid];
    z0_out[bg * 16 + tid] = z0v;
    float pm = pz0_mean[tid], pls = pz0_logstd[tid];
    float var_q = __expf(2.0f * qls);
    float var_p = __expf(2.0f * pls);
    float dm = qm - pm;
    float kl = pls - qls + (var_q + dm * dm) / (2.0f * var_p) - 0.5f;
    atomicAdd(&accums[5], kl);
  }
}

// ---------------------------------------------------------------------------
// Kernel 3: SDE scan.  (R10/R11-verified: ~790 us)  512 blocks x 256 threads,
// 1 batch/block, 2 blocks/CU, 3 LDS-only barriers/step, balanced phases,
// g-network via table lookup.
// ---------------------------------------------------------------------------
__global__ __launch_bounds__(256, 2) void k_sde(
    const f16* __restrict__ ctx, const float* __restrict__ z0_in,
    const float* __restrict__ ts, const float* __restrict__ bm_noise,
    const float* __restrict__ fw1, const float* __restrict__ fb1,
    const float* __restrict__ fw2, const float* __restrict__ fb2,
    const float* __restrict__ fw3, const float* __restrict__ fb3,
    const float* __restrict__ hw1, const float* __restrict__ hb1,
    const float* __restrict__ hw2, const float* __restrict__ hb2,
    const float* __restrict__ hw3, const float* __restrict__ hb3,
    const float* __restrict__ g_tab,
    f16* __restrict__ zs, float* __restrict__ accums) {
  __shared__ uint32_t s_x2[40];       // [z(8 u32) | ctx(32 u32)] f16x2
  __shared__ uint32_t s_h1[2][64];    // [mlp] layer-1 act, f16x2
  __shared__ uint32_t s_h2[2][64];    // [mlp] layer-2 act, f16x2
  __shared__ float s_dts[T_STEPS];

  const int tid = threadIdx.x;
  const int bg = blockIdx.x;
  const uint4* ctx4 = (const uint4*)ctx;

  const int r1 = tid >> 1, hh = tid & 1;
  const int mlp2 = tid >> 7, u2 = tid & 127;
  const int l3 = (tid >> 3) & 15;
  const int mlp3 = (tid >> 2) & 1;
  const int kq = tid & 3;
  const bool p3act = (tid < 128);
  const bool zlane = p3act && ((tid & 7) == 0);
  const bool stg = (tid >= 128 && tid < 136);

  // ---- weight preload
  uint32_t uw1f[20], uw1h[4], wP2[64], wP3[16];
  float bf1r, bh1r, bias2r, fb3r = 0.f, hb3r = 0.f;
  {
    const float* w = fw1 + (size_t)r1 * 80 + hh * 40;
#pragma unroll
    for (int i = 0; i < 20; ++i) uw1f[i] = packh2(w[2 * i], w[2 * i + 1]);
    bf1r = fb1[r1];
  }
  {
    const float* w = hw1 + (size_t)r1 * 16 + hh * 8;
#pragma unroll
    for (int i = 0; i < 4; ++i) uw1h[i] = packh2(w[2 * i], w[2 * i + 1]);
    bh1r = hb1[r1];
  }
  {
    const float* w = (mlp2 ? hw2 : fw2) + (size_t)u2 * 128;
#pragma unroll
    for (int i = 0; i < 64; ++i) wP2[i] = packh2(w[2 * i], w[2 * i + 1]);
    bias2r = (mlp2 ? hb2 : fb2)[u2];
  }
  if (p3act) {
    const float* w = (mlp3 ? hw3 : fw3) + (size_t)l3 * 128 + kq * 32;
#pragma unroll
    for (int i = 0; i < 16; ++i) wP3[i] = packh2(w[2 * i], w[2 * i + 1]);
    fb3r = fb3[l3];
    hb3r = hb3[l3];
  }
  for (int i = tid; i < T_STEPS - 1; i += 256) s_dts[i] = ts[i + 1] - ts[i];

  // ---- state init
  float zreg = 0.f, bmc = 0.f, path_acc = 0.f;
  uint4 cpref = make_uint4(0, 0, 0, 0);
  if (zlane) {
    zreg = z0_in[bg * 16 + l3];
    ((f16*)&s_x2[0])[l3] = (f16)zreg;
    zs[(size_t)bg * 16 + l3] = (f16)zreg;
    bmc = bm_noise[(size_t)bg * 16 + l3];
  }
  if (stg) {
    int q = tid - 128;
    uint4 v = ctx4[((size_t)1 * B_SZ + bg) * 8 + q];
    *(uint4*)&s_x2[8 + q * 4] = v;
  }
  __syncthreads();

  for (int t = 0; t < T_STEPS - 1; ++t) {
    float bmn = 0.f, gvp = 0.f;
    if (zlane) {
      unsigned short zb = __builtin_bit_cast(unsigned short, (f16)zreg);
      gvp = g_tab[l3 * 65536 + (int)zb];
      if (t < T_STEPS - 2)
        bmn = bm_noise[((size_t)(t + 1) * B_SZ + bg) * 16 + l3];
    }
    if (stg && t <= T_STEPS - 3)
      cpref = ctx4[((size_t)(t + 2) * B_SZ + bg) * 8 + (tid - 128)];

    // ---- P1: L1 balanced half-rows (all 256 threads)
    {
      const uint4* xq = (const uint4*)&s_x2[0];
      const int base = hh * 5;
      float a0 = 0.f, a1 = 0.f;
      {
        uint4 v0 = xq[base + 0], v1 = xq[base + 1];
        DOT4(a0, uw1f[0], uw1f[1], uw1f[2], uw1f[3], v0);
        DOT4(a1, uw1f[4], uw1f[5], uw1f[6], uw1f[7], v1);
        uint4 v2 = xq[base + 2], v3 = xq[base + 3];
        DOT4(a0, uw1f[8], uw1f[9], uw1f[10], uw1f[11], v2);
        DOT4(a1, uw1f[12], uw1f[13], uw1f[14], uw1f[15], v3);
        uint4 v4 = xq[base + 4];
        DOT4(a0, uw1f[16], uw1f[17], uw1f[18], uw1f[19], v4);
      }
      float af = a0 + a1;
      uint4 vz = xq[hh];
      float ah = 0.f;
      DOT4(ah, uw1h[0], uw1h[1], uw1h[2], uw1h[3], vz);
      float ff = af + __shfl_xor(af, 1);
      float fh = ah + __shfl_xor(ah, 1);
      if (hh == 0)
        ((f16*)&s_h1[0][0])[r1] = (f16)softplusf_(ff + bf1r);
      else
        ((f16*)&s_h1[1][0])[r1] = (f16)softplusf_(fh + bh1r);
    }
    barrier_lds();
    // ---- P2: L2 full rows (all 256 threads)
    {
      const uint4* hq = (const uint4*)&s_h1[mlp2][0];
      float a0 = 0.f, a1 = 0.f;
#pragma unroll
      for (int j = 0; j < 16; j += 2) {
        uint4 v0 = hq[j], v1 = hq[j + 1];
        DOT4(a0, wP2[4 * j], wP2[4 * j + 1], wP2[4 * j + 2], wP2[4 * j + 3], v0);
        DOT4(a1, wP2[4 * j + 4], wP2[4 * j + 5], wP2[4 * j + 6], wP2[4 * j + 7], v1);
      }
      ((f16*)&s_h2[mlp2][0])[u2] = (f16)softplusf_(a0 + a1 + bias2r);
    }
    barrier_lds();
    // ---- P3: L3 quarter-rows over 2 waves + z update; ctx stage
    if (p3act) {
      const uint4* hq = (const uint4*)&s_h2[mlp3][kq * 16];
      float a0 = 0.f, a1 = 0.f;
#pragma unroll
      for (int j = 0; j < 4; j += 2) {
        uint4 v0 = hq[j], v1 = hq[j + 1];
        DOT4(a0, wP3[4 * j], wP3[4 * j + 1], wP3[4 * j + 2], wP3[4 * j + 3], v0);
        DOT4(a1, wP3[4 * j + 4], wP3[4 * j + 5], wP3[4 * j + 6], wP3[4 * j + 7], v1);
      }
      float a = a0 + a1;
      float s1 = a + __shfl_xor(a, 1);
      float s2 = s1 + __shfl_xor(s1, 2);
      float other = __shfl_xor(s2, 4);
      if ((tid & 7) == 0) {
        float fv = s2 + fb3r;
        float hv = other + hb3r;
        float gv = gvp;
        float dt = s_dts[t];
        float u_ = (fv - hv) / gv;
        float ls = u_ * u_;
        ls += __shfl_xor(ls, 8);
        ls += __shfl_xor(ls, 16);
        ls += __shfl_xor(ls, 32);
        if ((tid & 63) == 0) path_acc += 0.5f * ls * dt;
        float dw = sqrtf(dt) * bmc;
        float zn = zreg + fv * dt + gv * dw;
        zreg = zn;
        ((f16*)&s_x2[0])[l3] = (f16)zn;
        zs[((size_t)(t + 1) * B_SZ + bg) * 16 + l3] = (f16)zn;
        bmc = bmn;
      }
    } else if (stg && t <= T_STEPS - 3) {
      *(uint4*)&s_x2[8 + (tid - 128) * 4] = cpref;
    }
    barrier_lds();
  }
  if (tid == 0 || tid == 64) atomicAdd(&accums[6], path_acc);
}

// ---------------------------------------------------------------------------
// Kernel 4: decoder + losses.  One thread per (t,b).
// ---------------------------------------------------------------------------
__global__ __launch_bounds__(256) void k_dec(
    const f16* __restrict__ zs, const f16* __restrict__ state_t,
    const float* __restrict__ xs, const float* __restrict__ proj_w,
    const float* __restrict__ proj_b, const float* __restrict__ act_w,
    const float* __restrict__ act_b, const float* __restrict__ land_w,
    const float* __restrict__ shot_w, const float* __restrict__ move_w,
    float* __restrict__ accums) {
  __shared__ uint32_t s_proj[8 * 32];
  __shared__ uint32_t s_act[8 * 128];
  __shared__ uint32_t s_head[128 * 8];
  __shared__ float s_pb[32], s_ab[128];
  __shared__ float s_red[4 * 5];

  const int tid = threadIdx.x;
  for (int id = tid; id < 8 * 32; id += 256) {
    int kp = id & 7, n = id >> 3;
    s_proj[kp * 32 + n] = packh2(proj_w[n * 16 + 2 * kp], proj_w[n * 16 + 2 * kp + 1]);
  }
  for (int id = tid; id < 8 * 128; id += 256) {
    int kp = id & 7, n = id >> 3;
    s_act[kp * 128 + n] = packh2(act_w[n * 16 + 2 * kp], act_w[n * 16 + 2 * kp + 1]);
  }
  for (int id = tid; id < 128 * 8; id += 256) {
    int j = id >> 3, p = id & 7;
    int h0 = 2 * p, h1 = 2 * p + 1;
    float w0 = (h0 < 2) ? land_w[h0 * 128 + j]
                        : (h0 < 14 ? shot_w[(h0 - 2) * 128 + j]
                                   : move_w[(h0 - 14) * 128 + j]);
    float w1 = (h1 < 2) ? land_w[h1 * 128 + j]
                        : (h1 < 14 ? shot_w[(h1 - 2) * 128 + j]
                                   : move_w[(h1 - 14) * 128 + j]);
    s_head[j * 8 + p] = packh2(w0, w1);
  }
  if (tid < 32) s_pb[tid] = proj_b[tid];
  if (tid < 128) s_ab[tid] = act_b[tid];
  __syncthreads();

  size_t idx = (size_t)blockIdx.x * 256 + tid;
  uint32_t z2[8];
  const uint32_t* zp = (const uint32_t*)(zs + idx * 16);
#pragma unroll
  for (int i = 0; i < 8; ++i) z2[i] = zp[i];
  uint32_t stv[16];
  const uint32_t* stp = (const uint32_t*)(state_t + idx * 32);
#pragma unroll
  for (int i = 0; i < 16; ++i) stv[i] = stp[i];

  float sqsum = 0.0f;
#pragma unroll 4
  for (int i = 0; i < 32; ++i) {
    float acc = s_pb[i];
#pragma unroll
    for (int kp = 0; kp < 8; ++kp) acc = fdot2(s_proj[kp * 32 + i], z2[kp], acc);
    f16x2 sv = __builtin_bit_cast(f16x2, stv[i >> 1]);
    float d = (float)sv[i & 1] - acc;
    sqsum += d * d;
  }

  float hd[16];
#pragma unroll
  for (int i = 0; i < 16; ++i) hd[i] = 0.0f;
#pragma unroll 2
  for (int j = 0; j < 128; ++j) {
    float a = s_ab[j];
#pragma unroll
    for (int kp = 0; kp < 8; ++kp) a = fdot2(s_act[kp * 128 + j], z2[kp], a);
    a = fmaxf(a, 0.0f);
#pragma unroll
    for (int p = 0; p < 8; ++p) {
      f16x2 w = __builtin_bit_cast(f16x2, s_head[j * 8 + p]);
      hd[2 * p] += (float)w[0] * a;
      hd[2 * p + 1] += (float)w[1] * a;
    }
  }
  const float* xp = xs + idx * 23;
  float dl0 = hd[0] - xp[18], dl1 = hd[1] - xp[19];
  float land = dl0 * dl0 + dl1 * dl1;
  float dm0 = hd[14] - xp[21], dm1 = hd[15] - xp[22];
  float move = dm0 * dm0 + dm1 * dm1;
  int sid = (int)xp[20];
  float m = hd[2];
#pragma unroll
  for (int s = 1; s < 12; ++s) m = fmaxf(m, hd[2 + s]);
  float sume = 0.0f;
#pragma unroll
  for (int s = 0; s < 12; ++s) sume += __expf(hd[2 + s] - m);
  float lse = m + __logf(sume);
  float pl = 0.0f;
#pragma unroll
  for (int s = 0; s < 12; ++s)
    if (s == sid) pl = hd[2 + s];
  float picked = 0.0f, cnt = 0.0f;
  if (sid != 0) {
    picked = pl - lse;
    cnt = 1.0f;
  }
  float vals[5] = {sqsum, land, move, picked, cnt};
#pragma unroll
  for (int v = 0; v < 5; ++v) {
    float x = vals[v];
    for (int off = 1; off < 64; off <<= 1) x += __shfl_xor(x, off);
    vals[v] = x;
  }
  int lane = tid & 63, wv = tid >> 6;
  if (lane == 0) {
#pragma unroll
    for (int v = 0; v < 5; ++v) s_red[wv * 5 + v] = vals[v];
  }
  __syncthreads();
  if (tid == 0) {
#pragma unroll
    for (int v = 0; v < 5; ++v) {
      float s = s_red[v] + s_red[5 + v] + s_red[10 + v] + s_red[15 + v];
      atomicAdd(&accums[v], s);
    }
  }
}

// ---------------------------------------------------------------------------
// Kernel 5: finalize the two scalar outputs.
// ---------------------------------------------------------------------------
__global__ void k_fin(const float* __restrict__ accums,
                      const float* __restrict__ noise_std,
                      float* __restrict__ out) {
  if (threadIdx.x == 0 && blockIdx.x == 0) {
    float sd = noise_std[0];
    float log_pxs = -0.5f * accums[0] / (sd * sd * (float)B_SZ) -
                    (float)T_STEPS * 32.0f * (logf(sd) + 0.5f * LOG2PI);
    float land = accums[1] / (float)(T_STEPS * B_SZ * 2);
    float move = accums[2] / (float)(T_STEPS * B_SZ * 2);
    float shot = -accums[3] / fmaxf(accums[4], 1.0f);
    float out1 = accums[5] / (float)B_SZ + accums[6] / (float)B_SZ + land + shot + move;
    out[0] = log_pxs;
    out[1] = out1;
  }
}

// ---------------------------------------------------------------------------
extern "C" void kernel_launch(void* const* d_in, const int* in_sizes, int n_in,
                              void* d_out, int out_size, void* d_ws,
                              size_t ws_size, hipStream_t stream) {
  const float* xs = (const float*)d_in[1];
  const float* ts = (const float*)d_in[2];
  const float* noise_std = (const float*)d_in[3];
  const float* z0_noise = (const float*)d_in[4];
  const float* bm_noise = (const float*)d_in[5];
  const float* shot_emb = (const float*)d_in[6];
  const float* player_emb = (const float*)d_in[7];
  const float* gru_wih = (const float*)d_in[8];
  const float* gru_whh = (const float*)d_in[9];
  const float* gru_bih = (const float*)d_in[10];
  const float* gru_bhh = (const float*)d_in[11];
  const float* enc_w = (const float*)d_in[12];
  const float* enc_b = (const float*)d_in[13];
  const float* qz0_w = (const float*)d_in[14];
  const float* qz0_b = (const float*)d_in[15];
  const float* f_w1 = (const float*)d_in[16];
  const float* f_b1 = (const float*)d_in[17];
  const float* f_w2 = (const float*)d_in[18];
  const float* f_b2 = (const float*)d_in[19];
  const float* f_w3 = (const float*)d_in[20];
  const float* f_b3 = (const float*)d_in[21];
  const float* h_w1 = (const float*)d_in[22];
  const float* h_b1 = (const float*)d_in[23];
  const float* h_w2 = (const float*)d_in[24];
  const float* h_b2 = (const float*)d_in[25];
  const float* h_w3 = (const float*)d_in[26];
  const float* h_b3 = (const float*)d_in[27];
  const float* g_w1 = (const float*)d_in[28];
  const float* g_b1 = (const float*)d_in[29];
  const float* g_w2 = (const float*)d_in[30];
  const float* g_b2 = (const float*)d_in[31];
  const float* proj_w = (const float*)d_in[32];
  const float* proj_b = (const float*)d_in[33];
  const float* pz0_mean = (const float*)d_in[34];
  const float* pz0_logstd = (const float*)d_in[35];
  const float* act_w = (const float*)d_in[36];
  const float* act_b = (const float*)d_in[37];
  const float* act_land_w = (const float*)d_in[38];
  const float* act_shot_w = (const float*)d_in[39];
  const float* act_move_w = (const float*)d_in[40];

  char* ws = (char*)d_ws;
  float* accums = (float*)ws;                       // 16 floats (256 B reserved)
  f16* state_t = (f16*)(ws + 256);                  // T*B*32 f16 = 16 MB
  f16* ctx = (f16*)(ws + 256 + 16777216);           // T*B*64 f16 = 32 MB
  float* z0b = (float*)(ws + 256 + 16777216 + 33554432);   // B*16 f32
  f16* zs = (f16*)(ws + 256 + 16777216 + 33554432 + 32768);  // T*B*16 f16 = 8 MB
  float* g_tab = (float*)(ws + 256 + 16777216 + 33554432 + 32768 + 8388608);  // 4 MB

  k_embed<<<1024, 256, 0, stream>>>(xs, shot_emb, player_emb, state_t, accums);
  k_gtab<<<4096, 256, 0, stream>>>(g_w1, g_b1, g_w2, g_b2, g_tab);
  k_gru<<<512, 256, 0, stream>>>(state_t, gru_wih, gru_whh, gru_bih, gru_bhh,
                                 enc_w, enc_b, qz0_w, qz0_b, z0_noise, pz0_mean,
                                 pz0_logstd, ctx, z0b, accums);
  k_sde<<<512, 256, 0, stream>>>(ctx, z0b, ts, bm_noise, f_w1, f_b1, f_w2, f_b2,
                                 f_w3, f_b3, h_w1, h_b1, h_w2, h_b2, h_w3, h_b3,
                                 g_tab, zs, accums);
  k_dec<<<1024, 256, 0, stream>>>(zs, state_t, xs, proj_w, proj_b, act_w, act_b,
                                  act_land_w, act_shot_w, act_move_w, accums);
  k_fin<<<1, 64, 0, stream>>>(accums, noise_std, (float*)d_out);
}